// Round 4
// baseline (826.891 us; speedup 1.0000x reference)
//
#include <hip/hip_runtime.h>
#include <hip/hip_bf16.h>
#include <cstdint>

// ---------------------------------------------------------------------------
// WorldModel RSSM: B=1024 T=50 E=1024 A=6 S=200 H=200 L=30
// fp32 in/out; internal GEMMs bf16 MFMA w/ fp32 accum.
//
//   k1: GI[bt,0:600]=concat(a,e)@W_ih+b_ih ; GI[bt,600:800]=e@Wq1[200:]+bq1
//       -> barrier-free: B-fragments read directly from L2-resident Bpack.
//   k2: GRU-only sequential scan (64 blocks x 13 waves, 16 rows each);
//       W_hh fragments preloaded in registers; GI prefetched one step ahead.
//   k3: heads (fc_prior/fc_posterior + softplus + rsample) fully parallel.
// ---------------------------------------------------------------------------

typedef __attribute__((ext_vector_type(8))) short   short8;
typedef __attribute__((ext_vector_type(8))) __bf16  bf16x8;
typedef __attribute__((ext_vector_type(4))) float   f32x4;

__device__ __forceinline__ float bf2f(unsigned short u) {
    unsigned int v = ((unsigned int)u) << 16;
    return __builtin_bit_cast(float, v);
}
__device__ __forceinline__ unsigned short f2bf(float f) {
    unsigned int v = __builtin_bit_cast(unsigned int, f);
    v = v + 0x7FFFu + ((v >> 16) & 1u);   // RNE
    return (unsigned short)(v >> 16);
}
__device__ __forceinline__ float softplusf(float x) {
    return (x > 20.f) ? x : log1pf(__expf(x));
}

// ---------------- workspace layout (bytes) ----------------
#define OFF_BPACK 81920000
#define OFF_WHH   83558400
#define OFF_WPQ1  83837952
#define OFF_WPQ2  84024320

// fragment mapping (mfma_f32_16x16x32_bf16):
//   A[l&15][(l>>4)*8+j], B[(l>>4)*8+j][l&15], D[(l>>4)*4+r][l&15]
// packed B storage: elem = ((kk*NT + nt)*64 + l)*8 + j

__global__ __launch_bounds__(256) void pack_kernel(
    const float* __restrict__ W_ih, const float* __restrict__ W_hh,
    const float* __restrict__ Wp1,  const float* __restrict__ Wq1,
    const float* __restrict__ Wp2,  const float* __restrict__ Wq2,
    unsigned short* __restrict__ Bpack, unsigned short* __restrict__ Whh_p,
    unsigned short* __restrict__ Wpq1,  unsigned short* __restrict__ Wpq2)
{
    int e = blockIdx.x * 256 + threadIdx.x;
    if (e < 819200) {                       // k1: K=1024(embed), N=800
        const int j = e & 7, l = (e >> 3) & 63;
        const int nt = (e >> 9) % 50, kk = e / (512 * 50);
        const int k = kk * 32 + (l >> 4) * 8 + j;
        const int c = nt * 16 + (l & 15);
        Bpack[e] = f2bf((c < 600) ? W_ih[(6 + k) * 600 + c]
                                  : Wq1[(200 + k) * 200 + (c - 600)]);
        return;
    }
    e -= 819200;
    if (e < 139776) {                       // W_hh: K pad 224, N = 3 gates x 13 tiles
        const int j = e & 7, l = (e >> 3) & 63;
        const int nt = (e >> 9) % 39, kk = e / (512 * 39);
        const int k = kk * 32 + (l >> 4) * 8 + j;
        const int g = nt / 13, st = nt % 13;
        const int c = st * 16 + (l & 15);
        Whh_p[e] = (k < 200 && c < 200) ? f2bf(W_hh[k * 600 + g * 200 + c]) : (unsigned short)0;
        return;
    }
    e -= 139776;
    if (e < 93184) {                        // heads1: [Wp1 | Wq1[:200]] K pad 224
        const int j = e & 7, l = (e >> 3) & 63;
        const int nt = (e >> 9) % 26, kk = e / (512 * 26);
        const int k = kk * 32 + (l >> 4) * 8 + j;
        unsigned short v = 0;
        if (nt < 13) { const int c = nt * 16 + (l & 15);        if (k < 200 && c < 200) v = f2bf(Wp1[k * 200 + c]); }
        else         { const int c = (nt - 13) * 16 + (l & 15); if (k < 200 && c < 200) v = f2bf(Wq1[k * 200 + c]); }
        Wpq1[e] = v;
        return;
    }
    e -= 93184;
    if (e < 28672) {                        // heads2: [Wp2 | Wq2] N pad 64 each
        const int j = e & 7, l = (e >> 3) & 63;
        const int nt = (e >> 9) % 8, kk = e / (512 * 8);
        const int k = kk * 32 + (l >> 4) * 8 + j;
        unsigned short v = 0;
        if (nt < 4) { const int c = nt * 16 + (l & 15);       if (k < 200 && c < 60) v = f2bf(Wp2[k * 60 + c]); }
        else        { const int c = (nt - 4) * 16 + (l & 15); if (k < 200 && c < 60) v = f2bf(Wq2[k * 60 + c]); }
        Wpq2[e] = v;
    }
}

// ---------------- kernel 1: GI/QE GEMM  M=51200 N=800 K=1024 ----------------
// Barrier-free, LDS-free. 512 thr = 8 waves: wave=(mp 0..1, nq 0..3);
// mp -> 2 M-subtiles, nq -> 13/12 N-tiles. B-fragments direct from L2 (Bpack
// is 1.6 MB, L2-resident). Compiler pipelines loads across kk (no barriers).
__global__ __launch_bounds__(512, 1) void k1_gi(
    const float* __restrict__ embed,   // [51200][1024]
    const float* __restrict__ action,  // [51200][6]
    const float* __restrict__ W_ih,    // rows 0..5 = action part
    const float* __restrict__ b_ih,
    const float* __restrict__ bq1,
    const unsigned short* __restrict__ Bpack,
    unsigned short* __restrict__ GI)   // [51200][800] bf16
{
    const int tid = threadIdx.x;
    const int w = tid >> 6, l = tid & 63;
    const int lo = l & 15, hi = l >> 4;
    const int mp = w >> 2, nq = w & 3;
    const int n0 = (nq < 2) ? nq * 13 : 26 + (nq - 2) * 12;
    const int nn = (nq < 2) ? 13 : 12;
    const size_t rowA0 = (size_t)(blockIdx.x * 64 + (2 * mp + 0) * 16 + lo);
    const size_t rowA1 = (size_t)(blockIdx.x * 64 + (2 * mp + 1) * 16 + lo);

    f32x4 acc[2][13];
#pragma unroll
    for (int p = 0; p < 2; ++p)
#pragma unroll
        for (int i = 0; i < 13; ++i) acc[p][i] = f32x4{0.f, 0.f, 0.f, 0.f};

    for (int kk = 0; kk < 32; ++kk) {
        // A-fragments (fp32 -> bf16 in-register) for both M-subtiles
        bf16x8 a[2];
#pragma unroll
        for (int p = 0; p < 2; ++p) {
            const float* ap = embed + (p ? rowA1 : rowA0) * 1024 + kk * 32 + hi * 8;
            f32x4 e0 = *(const f32x4*)ap;
            f32x4 e1 = *(const f32x4*)(ap + 4);
            bf16x8 av;
#pragma unroll
            for (int j = 0; j < 4; ++j) { av[j] = (__bf16)e0[j]; av[4 + j] = (__bf16)e1[j]; }
            a[p] = av;
        }
        const unsigned short* bp = Bpack + ((size_t)kk * 50 + n0) * 512 + l * 8;
#pragma unroll
        for (int i = 0; i < 13; ++i) if (i < nn) {
            bf16x8 b = __builtin_bit_cast(bf16x8, *(const short8*)(bp + i * 512));
            acc[0][i] = __builtin_amdgcn_mfma_f32_16x16x32_bf16(a[0], b, acc[0][i], 0, 0, 0);
            acc[1][i] = __builtin_amdgcn_mfma_f32_16x16x32_bf16(a[1], b, acc[1][i], 0, 0, 0);
        }
    }

    // epilogue: bias + action(K=6) contribution, store bf16
#pragma unroll
    for (int p = 0; p < 2; ++p) {
        const int rbase = blockIdx.x * 64 + (2 * mp + p) * 16 + hi * 4;
        float av[4][6];
#pragma unroll
        for (int r = 0; r < 4; ++r)
#pragma unroll
            for (int k = 0; k < 6; ++k) av[r][k] = action[(size_t)(rbase + r) * 6 + k];
#pragma unroll
        for (int i = 0; i < 13; ++i) if (i < nn) {
            const int col = (n0 + i) * 16 + lo;
            const float bias = (col < 600) ? b_ih[col] : bq1[col - 600];
            float wa[6];
            if (col < 600) {
#pragma unroll
                for (int k = 0; k < 6; ++k) wa[k] = W_ih[k * 600 + col];
            }
#pragma unroll
            for (int r = 0; r < 4; ++r) {
                float v = acc[p][i][r] + bias;
                if (col < 600) {
#pragma unroll
                    for (int k = 0; k < 6; ++k) v += av[r][k] * wa[k];
                }
                GI[(size_t)(rbase + r) * 800 + col] = f2bf(v);
            }
        }
    }
}

// ---------------- kernel 2: GRU-only sequential scan ----------------
// 64 blocks x 832 thr (13 waves). Wave w owns s-tile w (cols w*16..+15), all
// 3 gates. W_hh fragments preloaded in registers (21/wave, reused 50 steps);
// GI gate inputs prefetched one step ahead. 2 barriers/step.
#define HSTRB 232   // LDS row stride in bf16 elems (K pad >=224)

__global__ __launch_bounds__(832, 1) void k2_scan(
    unsigned short* __restrict__ GI,           // [51200][800] bf16 (deter -> cols 0..199)
    const unsigned short* __restrict__ Whh_p,
    const float* __restrict__ b_hh,
    float* __restrict__ out)                   // [51200][350] fp32 (cols 0..199 here)
{
    __shared__ unsigned short hS[16 * HSTRB];  // bf16 h, K-pad zeroed

    const int tid = threadIdx.x;
    const int w = tid >> 6, l = tid & 63;
    const int lo = l & 15, hi = l >> 4;
    const int r0 = blockIdx.x * 16;
    const int c = w * 16 + lo;                 // this thread's gate column
    const bool act = (c < 200);

    for (int i = tid; i < 16 * HSTRB; i += 832) hS[i] = 0;
    __syncthreads();

    // preload W_hh fragments: 3 gates x 7 k-slices (84 VGPR, live all 50 steps)
    bf16x8 wf[3][7];
#pragma unroll
    for (int g = 0; g < 3; ++g)
#pragma unroll
        for (int kk = 0; kk < 7; ++kk)
            wf[g][kk] = __builtin_bit_cast(bf16x8,
                *(const short8*)&Whh_p[((kk * 39 + g * 13 + w) * 64 + l) * 8]);

    float bh0 = 0.f, bh1 = 0.f, bh2 = 0.f;
    if (act) { bh0 = b_hh[c]; bh1 = b_hh[200 + c]; bh2 = b_hh[400 + c]; }
    float h_reg[4] = {0.f, 0.f, 0.f, 0.f};

    // prefetch GI gate inputs for t=0
    float cr[4], cz[4], cn[4];
    if (act) {
#pragma unroll
        for (int r = 0; r < 4; ++r) {
            const size_t gib = (size_t)((r0 + hi * 4 + r) * 50 + 0) * 800;
            cr[r] = bf2f(GI[gib + c]);
            cz[r] = bf2f(GI[gib + 200 + c]);
            cn[r] = bf2f(GI[gib + 400 + c]);
        }
    }

    for (int t = 0; t < 50; ++t) {
        // issue prefetch for t+1 (independent of everything below)
        float nr[4], nz[4], nx[4];
        const int tn = (t < 49) ? t + 1 : 49;
        if (act) {
#pragma unroll
            for (int r = 0; r < 4; ++r) {
                const size_t gib = (size_t)((r0 + hi * 4 + r) * 50 + tn) * 800;
                nr[r] = bf2f(GI[gib + c]);
                nz[r] = bf2f(GI[gib + 200 + c]);
                nx[r] = bf2f(GI[gib + 400 + c]);
            }
        }

        // A-fragments of h (bf16 direct from LDS)
        bf16x8 hf[7];
#pragma unroll
        for (int kk = 0; kk < 7; ++kk)
            hf[kk] = __builtin_bit_cast(bf16x8,
                *(const short8*)&hS[lo * HSTRB + kk * 32 + hi * 8]);

        // gh = h @ W_hh : 3 gates x 1 s-tile per wave (21 MFMA, regs only)
        f32x4 acc[3];
#pragma unroll
        for (int g = 0; g < 3; ++g) acc[g] = f32x4{0.f, 0.f, 0.f, 0.f};
#pragma unroll
        for (int g = 0; g < 3; ++g)
#pragma unroll
            for (int kk = 0; kk < 7; ++kk)
                acc[g] = __builtin_amdgcn_mfma_f32_16x16x32_bf16(hf[kk], wf[g][kk], acc[g], 0, 0, 0);

        float hnew[4];
        if (act) {
#pragma unroll
            for (int r = 0; r < 4; ++r) {
                const float gr = cr[r] + acc[0][r] + bh0;
                const float gz = cz[r] + acc[1][r] + bh1;
                const float hn = acc[2][r] + bh2;
                const float rr = 1.f / (1.f + __expf(-gr));
                const float zz = 1.f / (1.f + __expf(-gz));
                const float tt = tanhf(cn[r] + rr * hn);
                hnew[r] = (1.f - zz) * tt + zz * h_reg[r];
            }
        }
        __syncthreads();                       // B1: all hS reads of step t done
        if (act) {
#pragma unroll
            for (int r = 0; r < 4; ++r) {
                const int row = hi * 4 + r;
                const size_t bt = (size_t)((r0 + row) * 50 + t);
                h_reg[r] = hnew[r];
                hS[row * HSTRB + c] = f2bf(hnew[r]);
                out[bt * 350 + c] = hnew[r];               // deter fp32
                GI[bt * 800 + c]  = f2bf(hnew[r]);         // deter bf16 for k3
            }
        }
        __syncthreads();                       // B2: h' visible
#pragma unroll
        for (int r = 0; r < 4; ++r) { cr[r] = nr[r]; cz[r] = nz[r]; cn[r] = nx[r]; }
    }
}

// ---------------- kernel 3: heads, fully parallel over 51200 rows ----------------
__global__ __launch_bounds__(256, 1) void k3_heads(
    const unsigned short* __restrict__ GI,     // deter bf16 cols 0..199, QE cols 600..799
    const unsigned short* __restrict__ Wpq1,
    const unsigned short* __restrict__ Wpq2,
    const float* __restrict__ noise,           // [51200][30]
    const float* __restrict__ bp1,
    const float* __restrict__ bp2,
    const float* __restrict__ bq2,
    float* __restrict__ out)                   // cols 200..349
{
    __shared__ unsigned short pq[2][16 * HSTRB];  // [0]=elu prior h1, [1]=elu post h1
    __shared__ float ost[16 * 128];               // pm|ps|qm|qs raw

    const int tid = threadIdx.x;
    const int w = tid >> 6, l = tid & 63;
    const int lo = l & 15, hi = l >> 4;
    const int r0 = blockIdx.x * 16;

    {   unsigned short* p0 = &pq[0][0];
        for (int i = tid; i < 2 * 16 * HSTRB; i += 256) p0[i] = 0; }
    __syncthreads();

    // A-fragments: deter from GI (K pad 200..223 garbage x B-zero = safe)
    bf16x8 af[7];
#pragma unroll
    for (int kk = 0; kk < 7; ++kk)
        af[kk] = __builtin_bit_cast(bf16x8,
            *(const short8*)&GI[(size_t)(r0 + lo) * 800 + kk * 32 + hi * 8]);

    // heads1: 26 N-tiles over 4 waves (7/7/6/6)
    const int h1s = (w < 2) ? 7 * w : 14 + 6 * (w - 2);
    const int h1n = (w < 2) ? 7 : 6;
    f32x4 a2[7];
#pragma unroll
    for (int i = 0; i < 7; ++i) a2[i] = f32x4{0.f, 0.f, 0.f, 0.f};
#pragma unroll
    for (int i = 0; i < 7; ++i) if (i < h1n) {
        const int nt = h1s + i;
#pragma unroll
        for (int kk = 0; kk < 7; ++kk) {
            bf16x8 b = __builtin_bit_cast(bf16x8,
                *(const short8*)&Wpq1[((kk * 26 + nt) * 64 + l) * 8]);
            a2[i] = __builtin_amdgcn_mfma_f32_16x16x32_bf16(af[kk], b, a2[i], 0, 0, 0);
        }
    }
#pragma unroll
    for (int i = 0; i < 7; ++i) if (i < h1n) {
        const int nt = h1s + i;
        const bool isq = (nt >= 13);
        const int c1 = (isq ? (nt - 13) : nt) * 16 + lo;
        if (c1 < 200) {
#pragma unroll
            for (int r = 0; r < 4; ++r) {
                const int row = hi * 4 + r;
                float v = a2[i][r];
                if (isq) v += bf2f(GI[(size_t)(r0 + row) * 800 + 600 + c1]);  // QE (incl bq1)
                else     v += bp1[c1];
                v = (v > 0.f) ? v : expm1f(v);                                 // ELU
                pq[isq ? 1 : 0][row * HSTRB + c1] = f2bf(v);
            }
        }
    }
    __syncthreads();

    // heads2: waves 0,1 -> prior (tiles 0..3); waves 2,3 -> posterior (tiles 4..7)
    const unsigned short* srcS = &pq[(w >= 2) ? 1 : 0][0];
    bf16x8 pf[7];
#pragma unroll
    for (int kk = 0; kk < 7; ++kk)
        pf[kk] = __builtin_bit_cast(bf16x8,
            *(const short8*)&srcS[lo * HSTRB + kk * 32 + hi * 8]);
    f32x4 a3[2];
    a3[0] = f32x4{0.f, 0.f, 0.f, 0.f};
    a3[1] = f32x4{0.f, 0.f, 0.f, 0.f};
#pragma unroll
    for (int i = 0; i < 2; ++i) {
        const int nt = ((w >= 2) ? 4 : 0) + (w & 1) * 2 + i;
#pragma unroll
        for (int kk = 0; kk < 7; ++kk) {
            bf16x8 b = __builtin_bit_cast(bf16x8,
                *(const short8*)&Wpq2[((kk * 8 + nt) * 64 + l) * 8]);
            a3[i] = __builtin_amdgcn_mfma_f32_16x16x32_bf16(pf[kk], b, a3[i], 0, 0, 0);
        }
    }
#pragma unroll
    for (int i = 0; i < 2; ++i) {
        const int nt = ((w >= 2) ? 4 : 0) + (w & 1) * 2 + i;
        const int cl = (nt & 3) * 16 + lo;
        if (cl < 60) {
            const float bb = (nt < 4) ? bp2[cl] : bq2[cl];
            const int obase = ((nt < 4) ? 0 : 64) + ((cl < 30) ? cl : (32 + cl - 30));
#pragma unroll
            for (int r = 0; r < 4; ++r)
                ost[(hi * 4 + r) * 128 + obase] = a3[i][r] + bb;
        }
    }
    __syncthreads();

    // pack cols 200..349
    for (int idx = tid; idx < 16 * 150; idx += 256) {
        const int row = idx / 150;
        const int c = 200 + (idx - row * 150);
        const size_t bt = (size_t)(r0 + row);
        const float* o = &ost[row * 128];
        float v;
        if (c < 230) {
            const int j = c - 200;
            const float qs = softplusf(o[96 + j]) + 0.1f;
            v = o[64 + j] + qs * noise[bt * 30 + j];
        }
        else if (c < 260) v = o[c - 230];
        else if (c < 290) v = softplusf(o[32 + (c - 260)]) + 0.1f;
        else if (c < 320) v = o[64 + (c - 290)];
        else              v = softplusf(o[96 + (c - 320)]) + 0.1f;
        out[bt * 350 + c] = v;
    }
}

// ---------------------------------------------------------------------------
extern "C" void kernel_launch(void* const* d_in, const int* in_sizes, int n_in,
                              void* d_out, int out_size, void* d_ws, size_t ws_size,
                              hipStream_t stream)
{
    const float* action = (const float*)d_in[0];
    const float* embed  = (const float*)d_in[1];
    const float* noise  = (const float*)d_in[2];
    const float* W_ih   = (const float*)d_in[3];
    const float* W_hh   = (const float*)d_in[4];
    const float* b_ih   = (const float*)d_in[5];
    const float* b_hh   = (const float*)d_in[6];
    const float* Wp1    = (const float*)d_in[7];
    const float* bp1    = (const float*)d_in[8];
    const float* Wp2    = (const float*)d_in[9];
    const float* bp2    = (const float*)d_in[10];
    const float* Wq1    = (const float*)d_in[11];
    const float* bq1    = (const float*)d_in[12];
    const float* Wq2    = (const float*)d_in[13];
    const float* bq2    = (const float*)d_in[14];
    (void)in_sizes; (void)n_in; (void)out_size; (void)ws_size;

    char* ws = (char*)d_ws;
    unsigned short* GI    = (unsigned short*)(ws);
    unsigned short* Bpack = (unsigned short*)(ws + OFF_BPACK);
    unsigned short* Whh_p = (unsigned short*)(ws + OFF_WHH);
    unsigned short* Wpq1  = (unsigned short*)(ws + OFF_WPQ1);
    unsigned short* Wpq2  = (unsigned short*)(ws + OFF_WPQ2);
    float* outp = (float*)d_out;

    pack_kernel<<<4222, 256, 0, stream>>>(W_ih, W_hh, Wp1, Wq1, Wp2, Wq2,
                                          Bpack, Whh_p, Wpq1, Wpq2);
    k1_gi<<<800, 512, 0, stream>>>(embed, action, W_ih, b_ih, bq1, Bpack, GI);
    k2_scan<<<64, 832, 0, stream>>>(GI, Whh_p, b_hh, outp);
    k3_heads<<<3200, 256, 0, stream>>>(GI, Wpq1, Wpq2, noise, bp1, bp2, bq2, outp);
}

// Round 5
// 804.114 us; speedup vs baseline: 1.0283x; 1.0283x over previous
//
#include <hip/hip_runtime.h>
#include <hip/hip_bf16.h>
#include <cstdint>

// ---------------------------------------------------------------------------
// WorldModel RSSM: B=1024 T=50 E=1024 A=6 S=200 H=200 L=30
// fp32 in/out; internal GEMMs bf16 MFMA w/ fp32 accum.
//
//   k1: GI[bt,0:600]=concat(a,e)@W_ih+b_ih ; GI[bt,600:800]=e@Wq1[200:]+bq1
//       barrier-free; small register tile (2Mx7N) + launch_bounds(512,4)
//       -> 4 waves/SIMD to hide L2/HBM latency; A prefetched 1 kk ahead.
//   k2: GRU-only sequential scan (64 blocks x 13 waves, 16 rows each);
//       W_hh fragments preloaded in registers; GI prefetched one step ahead.
//   k3: heads (fc_prior/fc_posterior + softplus + rsample) fully parallel.
// ---------------------------------------------------------------------------

typedef __attribute__((ext_vector_type(8))) short   short8;
typedef __attribute__((ext_vector_type(8))) __bf16  bf16x8;
typedef __attribute__((ext_vector_type(4))) float   f32x4;

__device__ __forceinline__ float bf2f(unsigned short u) {
    unsigned int v = ((unsigned int)u) << 16;
    return __builtin_bit_cast(float, v);
}
__device__ __forceinline__ unsigned short f2bf(float f) {
    unsigned int v = __builtin_bit_cast(unsigned int, f);
    v = v + 0x7FFFu + ((v >> 16) & 1u);   // RNE
    return (unsigned short)(v >> 16);
}
__device__ __forceinline__ float softplusf(float x) {
    return (x > 20.f) ? x : log1pf(__expf(x));
}

// ---------------- workspace layout (bytes) ----------------
#define OFF_BPACK 81920000
#define OFF_WHH   83558400
#define OFF_WPQ1  83837952
#define OFF_WPQ2  84024320

// fragment mapping (mfma_f32_16x16x32_bf16):
//   A[l&15][(l>>4)*8+j], B[(l>>4)*8+j][l&15], D[(l>>4)*4+r][l&15]
// packed B storage: elem = ((kk*NT + nt)*64 + l)*8 + j

__global__ __launch_bounds__(256) void pack_kernel(
    const float* __restrict__ W_ih, const float* __restrict__ W_hh,
    const float* __restrict__ Wp1,  const float* __restrict__ Wq1,
    const float* __restrict__ Wp2,  const float* __restrict__ Wq2,
    unsigned short* __restrict__ Bpack, unsigned short* __restrict__ Whh_p,
    unsigned short* __restrict__ Wpq1,  unsigned short* __restrict__ Wpq2)
{
    int e = blockIdx.x * 256 + threadIdx.x;
    if (e < 819200) {                       // k1: K=1024(embed), N=800
        const int j = e & 7, l = (e >> 3) & 63;
        const int nt = (e >> 9) % 50, kk = e / (512 * 50);
        const int k = kk * 32 + (l >> 4) * 8 + j;
        const int c = nt * 16 + (l & 15);
        Bpack[e] = f2bf((c < 600) ? W_ih[(6 + k) * 600 + c]
                                  : Wq1[(200 + k) * 200 + (c - 600)]);
        return;
    }
    e -= 819200;
    if (e < 139776) {                       // W_hh: K pad 224, N = 3 gates x 13 tiles
        const int j = e & 7, l = (e >> 3) & 63;
        const int nt = (e >> 9) % 39, kk = e / (512 * 39);
        const int k = kk * 32 + (l >> 4) * 8 + j;
        const int g = nt / 13, st = nt % 13;
        const int c = st * 16 + (l & 15);
        Whh_p[e] = (k < 200 && c < 200) ? f2bf(W_hh[k * 600 + g * 200 + c]) : (unsigned short)0;
        return;
    }
    e -= 139776;
    if (e < 93184) {                        // heads1: [Wp1 | Wq1[:200]] K pad 224
        const int j = e & 7, l = (e >> 3) & 63;
        const int nt = (e >> 9) % 26, kk = e / (512 * 26);
        const int k = kk * 32 + (l >> 4) * 8 + j;
        unsigned short v = 0;
        if (nt < 13) { const int c = nt * 16 + (l & 15);        if (k < 200 && c < 200) v = f2bf(Wp1[k * 200 + c]); }
        else         { const int c = (nt - 13) * 16 + (l & 15); if (k < 200 && c < 200) v = f2bf(Wq1[k * 200 + c]); }
        Wpq1[e] = v;
        return;
    }
    e -= 93184;
    if (e < 28672) {                        // heads2: [Wp2 | Wq2] N pad 64 each
        const int j = e & 7, l = (e >> 3) & 63;
        const int nt = (e >> 9) % 8, kk = e / (512 * 8);
        const int k = kk * 32 + (l >> 4) * 8 + j;
        unsigned short v = 0;
        if (nt < 4) { const int c = nt * 16 + (l & 15);       if (k < 200 && c < 60) v = f2bf(Wp2[k * 60 + c]); }
        else        { const int c = (nt - 4) * 16 + (l & 15); if (k < 200 && c < 60) v = f2bf(Wq2[k * 60 + c]); }
        Wpq2[e] = v;
    }
}

// ---------------- kernel 1: GI/QE GEMM  M=51200 N=800 K=1024 ----------------
// Barrier-free, LDS-free. grid 1600 = 800 M-chunks x 2 N-halves.
// 512 thr = 8 waves = (mp 0..1) x (nq 0..3). Wave = 2 M-subtiles x 7/6 N-tiles
// (acc 56 AGPR). launch_bounds(512,4) forces <=128 regs -> 4 waves/SIMD.
// A (embed fp32) prefetched one kk ahead; B direct from L2-resident Bpack.
__global__ __launch_bounds__(512, 4) void k1_gi(
    const float* __restrict__ embed,   // [51200][1024]
    const float* __restrict__ action,  // [51200][6]
    const float* __restrict__ W_ih,    // rows 0..5 = action part
    const float* __restrict__ b_ih,
    const float* __restrict__ bq1,
    const unsigned short* __restrict__ Bpack,
    unsigned short* __restrict__ GI)   // [51200][800] bf16
{
    const int tid = threadIdx.x;
    const int w = tid >> 6, l = tid & 63;
    const int lo = l & 15, hi = l >> 4;
    const int mp = w >> 2, nq = w & 3;
    const int mblk = blockIdx.x >> 1;          // 0..799
    const int half = blockIdx.x & 1;           // 0..1 (N-halves of 25 tiles)
    const int n0 = half * 25 + ((nq == 0) ? 0 : 7 + (nq - 1) * 6);
    const int nn = (nq == 0) ? 7 : 6;
    const int rb0 = mblk * 64 + (mp * 2 + 0) * 16;
    const int rb1 = mblk * 64 + (mp * 2 + 1) * 16;

    const float* ap0 = embed + (size_t)(rb0 + lo) * 1024 + hi * 8;
    const float* ap1 = embed + (size_t)(rb1 + lo) * 1024 + hi * 8;

    f32x4 acc[2][7];
#pragma unroll
    for (int p = 0; p < 2; ++p)
#pragma unroll
        for (int i = 0; i < 7; ++i) acc[p][i] = f32x4{0.f, 0.f, 0.f, 0.f};

    // prefetch A for kk=0
    f32x4 e00 = *(const f32x4*)(ap0);
    f32x4 e01 = *(const f32x4*)(ap0 + 4);
    f32x4 e10 = *(const f32x4*)(ap1);
    f32x4 e11 = *(const f32x4*)(ap1 + 4);

#pragma unroll 4
    for (int kk = 0; kk < 32; ++kk) {
        // convert current A to bf16 fragments
        bf16x8 a0, a1;
#pragma unroll
        for (int j = 0; j < 4; ++j) {
            a0[j] = (__bf16)e00[j]; a0[4 + j] = (__bf16)e01[j];
            a1[j] = (__bf16)e10[j]; a1[4 + j] = (__bf16)e11[j];
        }
        // prefetch A for kk+1 (hidden under this kk's MFMAs)
        if (kk < 31) {
            const float* p0 = ap0 + (kk + 1) * 32;
            const float* p1 = ap1 + (kk + 1) * 32;
            e00 = *(const f32x4*)(p0);
            e01 = *(const f32x4*)(p0 + 4);
            e10 = *(const f32x4*)(p1);
            e11 = *(const f32x4*)(p1 + 4);
        }
        const unsigned short* bp = Bpack + ((size_t)kk * 50 + n0) * 512 + l * 8;
#pragma unroll
        for (int i = 0; i < 7; ++i) if (i < nn) {
            bf16x8 b = __builtin_bit_cast(bf16x8, *(const short8*)(bp + i * 512));
            acc[0][i] = __builtin_amdgcn_mfma_f32_16x16x32_bf16(a0, b, acc[0][i], 0, 0, 0);
            acc[1][i] = __builtin_amdgcn_mfma_f32_16x16x32_bf16(a1, b, acc[1][i], 0, 0, 0);
        }
    }

    // epilogue: bias + action(K=6) contribution, store bf16
#pragma unroll
    for (int p = 0; p < 2; ++p) {
        const int rbase = (p ? rb1 : rb0) + hi * 4;
        float av[4][6];
#pragma unroll
        for (int r = 0; r < 4; ++r)
#pragma unroll
            for (int k = 0; k < 6; ++k) av[r][k] = action[(size_t)(rbase + r) * 6 + k];
#pragma unroll
        for (int i = 0; i < 7; ++i) if (i < nn) {
            const int col = (n0 + i) * 16 + lo;
            const float bias = (col < 600) ? b_ih[col] : bq1[col - 600];
            float wa[6];
            if (col < 600) {
#pragma unroll
                for (int k = 0; k < 6; ++k) wa[k] = W_ih[k * 600 + col];
            }
#pragma unroll
            for (int r = 0; r < 4; ++r) {
                float v = acc[p][i][r] + bias;
                if (col < 600) {
#pragma unroll
                    for (int k = 0; k < 6; ++k) v += av[r][k] * wa[k];
                }
                GI[(size_t)(rbase + r) * 800 + col] = f2bf(v);
            }
        }
    }
}

// ---------------- kernel 2: GRU-only sequential scan ----------------
// 64 blocks x 832 thr (13 waves). Wave w owns s-tile w (cols w*16..+15), all
// 3 gates. W_hh fragments preloaded in registers (21/wave, reused 50 steps);
// GI gate inputs prefetched one step ahead. 2 barriers/step.
#define HSTRB 232   // LDS row stride in bf16 elems (K pad >=224)

__global__ __launch_bounds__(832, 1) void k2_scan(
    unsigned short* __restrict__ GI,           // [51200][800] bf16 (deter -> cols 0..199)
    const unsigned short* __restrict__ Whh_p,
    const float* __restrict__ b_hh,
    float* __restrict__ out)                   // [51200][350] fp32 (cols 0..199 here)
{
    __shared__ unsigned short hS[16 * HSTRB];  // bf16 h, K-pad zeroed

    const int tid = threadIdx.x;
    const int w = tid >> 6, l = tid & 63;
    const int lo = l & 15, hi = l >> 4;
    const int r0 = blockIdx.x * 16;
    const int c = w * 16 + lo;                 // this thread's gate column
    const bool act = (c < 200);

    for (int i = tid; i < 16 * HSTRB; i += 832) hS[i] = 0;
    __syncthreads();

    // preload W_hh fragments: 3 gates x 7 k-slices (84 VGPR, live all 50 steps)
    bf16x8 wf[3][7];
#pragma unroll
    for (int g = 0; g < 3; ++g)
#pragma unroll
        for (int kk = 0; kk < 7; ++kk)
            wf[g][kk] = __builtin_bit_cast(bf16x8,
                *(const short8*)&Whh_p[((kk * 39 + g * 13 + w) * 64 + l) * 8]);

    float bh0 = 0.f, bh1 = 0.f, bh2 = 0.f;
    if (act) { bh0 = b_hh[c]; bh1 = b_hh[200 + c]; bh2 = b_hh[400 + c]; }
    float h_reg[4] = {0.f, 0.f, 0.f, 0.f};

    // prefetch GI gate inputs for t=0
    float cr[4], cz[4], cn[4];
    if (act) {
#pragma unroll
        for (int r = 0; r < 4; ++r) {
            const size_t gib = (size_t)((r0 + hi * 4 + r) * 50 + 0) * 800;
            cr[r] = bf2f(GI[gib + c]);
            cz[r] = bf2f(GI[gib + 200 + c]);
            cn[r] = bf2f(GI[gib + 400 + c]);
        }
    }

    for (int t = 0; t < 50; ++t) {
        // issue prefetch for t+1 (independent of everything below)
        float nr[4], nz[4], nx[4];
        const int tn = (t < 49) ? t + 1 : 49;
        if (act) {
#pragma unroll
            for (int r = 0; r < 4; ++r) {
                const size_t gib = (size_t)((r0 + hi * 4 + r) * 50 + tn) * 800;
                nr[r] = bf2f(GI[gib + c]);
                nz[r] = bf2f(GI[gib + 200 + c]);
                nx[r] = bf2f(GI[gib + 400 + c]);
            }
        }

        // A-fragments of h (bf16 direct from LDS)
        bf16x8 hf[7];
#pragma unroll
        for (int kk = 0; kk < 7; ++kk)
            hf[kk] = __builtin_bit_cast(bf16x8,
                *(const short8*)&hS[lo * HSTRB + kk * 32 + hi * 8]);

        // gh = h @ W_hh : 3 gates x 1 s-tile per wave (21 MFMA, regs only)
        f32x4 acc[3];
#pragma unroll
        for (int g = 0; g < 3; ++g) acc[g] = f32x4{0.f, 0.f, 0.f, 0.f};
#pragma unroll
        for (int g = 0; g < 3; ++g)
#pragma unroll
            for (int kk = 0; kk < 7; ++kk)
                acc[g] = __builtin_amdgcn_mfma_f32_16x16x32_bf16(hf[kk], wf[g][kk], acc[g], 0, 0, 0);

        float hnew[4];
        if (act) {
#pragma unroll
            for (int r = 0; r < 4; ++r) {
                const float gr = cr[r] + acc[0][r] + bh0;
                const float gz = cz[r] + acc[1][r] + bh1;
                const float hn = acc[2][r] + bh2;
                const float rr = 1.f / (1.f + __expf(-gr));
                const float zz = 1.f / (1.f + __expf(-gz));
                const float tt = tanhf(cn[r] + rr * hn);
                hnew[r] = (1.f - zz) * tt + zz * h_reg[r];
            }
        }
        __syncthreads();                       // B1: all hS reads of step t done
        if (act) {
#pragma unroll
            for (int r = 0; r < 4; ++r) {
                const int row = hi * 4 + r;
                const size_t bt = (size_t)((r0 + row) * 50 + t);
                h_reg[r] = hnew[r];
                hS[row * HSTRB + c] = f2bf(hnew[r]);
                out[bt * 350 + c] = hnew[r];               // deter fp32
                GI[bt * 800 + c]  = f2bf(hnew[r]);         // deter bf16 for k3
            }
        }
        __syncthreads();                       // B2: h' visible
#pragma unroll
        for (int r = 0; r < 4; ++r) { cr[r] = nr[r]; cz[r] = nz[r]; cn[r] = nx[r]; }
    }
}

// ---------------- kernel 3: heads, fully parallel over 51200 rows ----------------
__global__ __launch_bounds__(256, 1) void k3_heads(
    const unsigned short* __restrict__ GI,     // deter bf16 cols 0..199, QE cols 600..799
    const unsigned short* __restrict__ Wpq1,
    const unsigned short* __restrict__ Wpq2,
    const float* __restrict__ noise,           // [51200][30]
    const float* __restrict__ bp1,
    const float* __restrict__ bp2,
    const float* __restrict__ bq2,
    float* __restrict__ out)                   // cols 200..349
{
    __shared__ unsigned short pq[2][16 * HSTRB];  // [0]=elu prior h1, [1]=elu post h1
    __shared__ float ost[16 * 128];               // pm|ps|qm|qs raw

    const int tid = threadIdx.x;
    const int w = tid >> 6, l = tid & 63;
    const int lo = l & 15, hi = l >> 4;
    const int r0 = blockIdx.x * 16;

    {   unsigned short* p0 = &pq[0][0];
        for (int i = tid; i < 2 * 16 * HSTRB; i += 256) p0[i] = 0; }
    __syncthreads();

    // A-fragments: deter from GI (K pad 200..223 garbage x B-zero = safe)
    bf16x8 af[7];
#pragma unroll
    for (int kk = 0; kk < 7; ++kk)
        af[kk] = __builtin_bit_cast(bf16x8,
            *(const short8*)&GI[(size_t)(r0 + lo) * 800 + kk * 32 + hi * 8]);

    // heads1: 26 N-tiles over 4 waves (7/7/6/6)
    const int h1s = (w < 2) ? 7 * w : 14 + 6 * (w - 2);
    const int h1n = (w < 2) ? 7 : 6;
    f32x4 a2[7];
#pragma unroll
    for (int i = 0; i < 7; ++i) a2[i] = f32x4{0.f, 0.f, 0.f, 0.f};
#pragma unroll
    for (int i = 0; i < 7; ++i) if (i < h1n) {
        const int nt = h1s + i;
#pragma unroll
        for (int kk = 0; kk < 7; ++kk) {
            bf16x8 b = __builtin_bit_cast(bf16x8,
                *(const short8*)&Wpq1[((kk * 26 + nt) * 64 + l) * 8]);
            a2[i] = __builtin_amdgcn_mfma_f32_16x16x32_bf16(af[kk], b, a2[i], 0, 0, 0);
        }
    }
#pragma unroll
    for (int i = 0; i < 7; ++i) if (i < h1n) {
        const int nt = h1s + i;
        const bool isq = (nt >= 13);
        const int c1 = (isq ? (nt - 13) : nt) * 16 + lo;
        if (c1 < 200) {
#pragma unroll
            for (int r = 0; r < 4; ++r) {
                const int row = hi * 4 + r;
                float v = a2[i][r];
                if (isq) v += bf2f(GI[(size_t)(r0 + row) * 800 + 600 + c1]);  // QE (incl bq1)
                else     v += bp1[c1];
                v = (v > 0.f) ? v : expm1f(v);                                 // ELU
                pq[isq ? 1 : 0][row * HSTRB + c1] = f2bf(v);
            }
        }
    }
    __syncthreads();

    // heads2: waves 0,1 -> prior (tiles 0..3); waves 2,3 -> posterior (tiles 4..7)
    const unsigned short* srcS = &pq[(w >= 2) ? 1 : 0][0];
    bf16x8 pf[7];
#pragma unroll
    for (int kk = 0; kk < 7; ++kk)
        pf[kk] = __builtin_bit_cast(bf16x8,
            *(const short8*)&srcS[lo * HSTRB + kk * 32 + hi * 8]);
    f32x4 a3[2];
    a3[0] = f32x4{0.f, 0.f, 0.f, 0.f};
    a3[1] = f32x4{0.f, 0.f, 0.f, 0.f};
#pragma unroll
    for (int i = 0; i < 2; ++i) {
        const int nt = ((w >= 2) ? 4 : 0) + (w & 1) * 2 + i;
#pragma unroll
        for (int kk = 0; kk < 7; ++kk) {
            bf16x8 b = __builtin_bit_cast(bf16x8,
                *(const short8*)&Wpq2[((kk * 8 + nt) * 64 + l) * 8]);
            a3[i] = __builtin_amdgcn_mfma_f32_16x16x32_bf16(pf[kk], b, a3[i], 0, 0, 0);
        }
    }
#pragma unroll
    for (int i = 0; i < 2; ++i) {
        const int nt = ((w >= 2) ? 4 : 0) + (w & 1) * 2 + i;
        const int cl = (nt & 3) * 16 + lo;
        if (cl < 60) {
            const float bb = (nt < 4) ? bp2[cl] : bq2[cl];
            const int obase = ((nt < 4) ? 0 : 64) + ((cl < 30) ? cl : (32 + cl - 30));
#pragma unroll
            for (int r = 0; r < 4; ++r)
                ost[(hi * 4 + r) * 128 + obase] = a3[i][r] + bb;
        }
    }
    __syncthreads();

    // pack cols 200..349
    for (int idx = tid; idx < 16 * 150; idx += 256) {
        const int row = idx / 150;
        const int c = 200 + (idx - row * 150);
        const size_t bt = (size_t)(r0 + row);
        const float* o = &ost[row * 128];
        float v;
        if (c < 230) {
            const int j = c - 200;
            const float qs = softplusf(o[96 + j]) + 0.1f;
            v = o[64 + j] + qs * noise[bt * 30 + j];
        }
        else if (c < 260) v = o[c - 230];
        else if (c < 290) v = softplusf(o[32 + (c - 260)]) + 0.1f;
        else if (c < 320) v = o[64 + (c - 290)];
        else              v = softplusf(o[96 + (c - 320)]) + 0.1f;
        out[bt * 350 + c] = v;
    }
}

// ---------------------------------------------------------------------------
extern "C" void kernel_launch(void* const* d_in, const int* in_sizes, int n_in,
                              void* d_out, int out_size, void* d_ws, size_t ws_size,
                              hipStream_t stream)
{
    const float* action = (const float*)d_in[0];
    const float* embed  = (const float*)d_in[1];
    const float* noise  = (const float*)d_in[2];
    const float* W_ih   = (const float*)d_in[3];
    const float* W_hh   = (const float*)d_in[4];
    const float* b_ih   = (const float*)d_in[5];
    const float* b_hh   = (const float*)d_in[6];
    const float* Wp1    = (const float*)d_in[7];
    const float* bp1    = (const float*)d_in[8];
    const float* Wp2    = (const float*)d_in[9];
    const float* bp2    = (const float*)d_in[10];
    const float* Wq1    = (const float*)d_in[11];
    const float* bq1    = (const float*)d_in[12];
    const float* Wq2    = (const float*)d_in[13];
    const float* bq2    = (const float*)d_in[14];
    (void)in_sizes; (void)n_in; (void)out_size; (void)ws_size;

    char* ws = (char*)d_ws;
    unsigned short* GI    = (unsigned short*)(ws);
    unsigned short* Bpack = (unsigned short*)(ws + OFF_BPACK);
    unsigned short* Whh_p = (unsigned short*)(ws + OFF_WHH);
    unsigned short* Wpq1  = (unsigned short*)(ws + OFF_WPQ1);
    unsigned short* Wpq2  = (unsigned short*)(ws + OFF_WPQ2);
    float* outp = (float*)d_out;

    pack_kernel<<<4222, 256, 0, stream>>>(W_ih, W_hh, Wp1, Wq1, Wp2, Wq2,
                                          Bpack, Whh_p, Wpq1, Wpq2);
    k1_gi<<<1600, 512, 0, stream>>>(embed, action, W_ih, b_ih, bq1, Bpack, GI);
    k2_scan<<<64, 832, 0, stream>>>(GI, Whh_p, b_hh, outp);
    k3_heads<<<3200, 256, 0, stream>>>(GI, Wpq1, Wpq2, noise, bp1, bp2, bq2, outp);
}

// Round 6
// 667.846 us; speedup vs baseline: 1.2381x; 1.2040x over previous
//
#include <hip/hip_runtime.h>
#include <hip/hip_bf16.h>
#include <cstdint>

// ---------------------------------------------------------------------------
// WorldModel RSSM: B=1024 T=50 E=1024 A=6 S=200 H=200 L=30
// fp32 in/out; internal GEMMs bf16 MFMA w/ fp32 accum.
//
//   k1: GI[bt,0:600]=concat(a,e)@W_ih+b_ih ; GI[bt,600:800]=e@Wq1[200:]+bq1
//       2-phase double-buffered LDS pipeline (T3-minimum): B staged via
//       global_load_lds(16B), A reg-staged fp32->bf16; 1 barrier per K-step.
//   k2: GRU-only sequential scan (64 blocks x 13 waves, 16 rows each).
//   k3: heads (fc_prior/fc_posterior + softplus + rsample) fully parallel.
// ---------------------------------------------------------------------------

typedef __attribute__((ext_vector_type(8))) short   short8;
typedef __attribute__((ext_vector_type(8))) __bf16  bf16x8;
typedef __attribute__((ext_vector_type(4))) float   f32x4;

__device__ __forceinline__ float bf2f(unsigned short u) {
    unsigned int v = ((unsigned int)u) << 16;
    return __builtin_bit_cast(float, v);
}
__device__ __forceinline__ unsigned short f2bf(float f) {
    unsigned int v = __builtin_bit_cast(unsigned int, f);
    v = v + 0x7FFFu + ((v >> 16) & 1u);   // RNE
    return (unsigned short)(v >> 16);
}
__device__ __forceinline__ float softplusf(float x) {
    return (x > 20.f) ? x : log1pf(__expf(x));
}
__device__ __forceinline__ void gload_lds16(const void* g, void* l) {
    __builtin_amdgcn_global_load_lds(
        (const __attribute__((address_space(1))) void*)g,
        (__attribute__((address_space(3))) void*)l, 16, 0, 0);
}

// ---------------- workspace layout (bytes) ----------------
#define OFF_BPACK 81920000
#define OFF_WHH   83558400
#define OFF_WPQ1  83837952
#define OFF_WPQ2  84024320

// fragment mapping (mfma_f32_16x16x32_bf16):
//   A[l&15][(l>>4)*8+j], B[(l>>4)*8+j][l&15], D[(l>>4)*4+r][l&15]
// packed B storage: elem = ((kk*NT + nt)*64 + l)*8 + j

__global__ __launch_bounds__(256) void pack_kernel(
    const float* __restrict__ W_ih, const float* __restrict__ W_hh,
    const float* __restrict__ Wp1,  const float* __restrict__ Wq1,
    const float* __restrict__ Wp2,  const float* __restrict__ Wq2,
    unsigned short* __restrict__ Bpack, unsigned short* __restrict__ Whh_p,
    unsigned short* __restrict__ Wpq1,  unsigned short* __restrict__ Wpq2)
{
    int e = blockIdx.x * 256 + threadIdx.x;
    if (e < 819200) {                       // k1: K=1024(embed), N=800
        const int j = e & 7, l = (e >> 3) & 63;
        const int nt = (e >> 9) % 50, kk = e / (512 * 50);
        const int k = kk * 32 + (l >> 4) * 8 + j;
        const int c = nt * 16 + (l & 15);
        Bpack[e] = f2bf((c < 600) ? W_ih[(6 + k) * 600 + c]
                                  : Wq1[(200 + k) * 200 + (c - 600)]);
        return;
    }
    e -= 819200;
    if (e < 139776) {                       // W_hh: K pad 224, N = 3 gates x 13 tiles
        const int j = e & 7, l = (e >> 3) & 63;
        const int nt = (e >> 9) % 39, kk = e / (512 * 39);
        const int k = kk * 32 + (l >> 4) * 8 + j;
        const int g = nt / 13, st = nt % 13;
        const int c = st * 16 + (l & 15);
        Whh_p[e] = (k < 200 && c < 200) ? f2bf(W_hh[k * 600 + g * 200 + c]) : (unsigned short)0;
        return;
    }
    e -= 139776;
    if (e < 93184) {                        // heads1: [Wp1 | Wq1[:200]] K pad 224
        const int j = e & 7, l = (e >> 3) & 63;
        const int nt = (e >> 9) % 26, kk = e / (512 * 26);
        const int k = kk * 32 + (l >> 4) * 8 + j;
        unsigned short v = 0;
        if (nt < 13) { const int c = nt * 16 + (l & 15);        if (k < 200 && c < 200) v = f2bf(Wp1[k * 200 + c]); }
        else         { const int c = (nt - 13) * 16 + (l & 15); if (k < 200 && c < 200) v = f2bf(Wq1[k * 200 + c]); }
        Wpq1[e] = v;
        return;
    }
    e -= 93184;
    if (e < 28672) {                        // heads2: [Wp2 | Wq2] N pad 64 each
        const int j = e & 7, l = (e >> 3) & 63;
        const int nt = (e >> 9) % 8, kk = e / (512 * 8);
        const int k = kk * 32 + (l >> 4) * 8 + j;
        unsigned short v = 0;
        if (nt < 4) { const int c = nt * 16 + (l & 15);       if (k < 200 && c < 60) v = f2bf(Wp2[k * 60 + c]); }
        else        { const int c = (nt - 4) * 16 + (l & 15); if (k < 200 && c < 60) v = f2bf(Wq2[k * 60 + c]); }
        Wpq2[e] = v;
    }
}

// ---------------- kernel 1: GI/QE GEMM  M=51200 N=800 K=1024 ----------------
// grid 1600 = 800 M-chunks(64 rows) x 2 N-halves(400 cols = 25 tiles).
// 512 thr = 8 waves = (mp 0..3) x (nq 0..1); wave = 16 rows x 13/12 N-tiles.
// 2-phase pipeline: stage(kk+1) issued before compute(kk); 1 barrier/kk
// (its implicit vmcnt(0) drain completes the prefetch).
__global__ __launch_bounds__(512, 4) void k1_gi(
    const float* __restrict__ embed,   // [51200][1024]
    const float* __restrict__ action,  // [51200][6]
    const float* __restrict__ W_ih,    // rows 0..5 = action part
    const float* __restrict__ b_ih,
    const float* __restrict__ bq1,
    const unsigned short* __restrict__ Bpack,
    unsigned short* __restrict__ GI)   // [51200][800] bf16
{
    __shared__ unsigned short Bb[2][12800];   // 25 tiles x 512 shorts, dbuf
    __shared__ unsigned short Ab[2][2048];    // 4 mp-frags x 512 shorts, dbuf

    const int tid = threadIdx.x;
    const int w = tid >> 6, l = tid & 63;
    const int lo = l & 15, hi = l >> 4;
    const int mp = w >> 1, nq = w & 1;
    const int mblk = blockIdx.x >> 1;          // 0..799
    const int half = blockIdx.x & 1;           // 0..1
    const int tb = nq * 13;                    // local tile base (0 or 13)
    const int nn = nq ? 12 : 13;
    const int rb = mblk * 64;

    // B source for this half (25 contiguous tiles per kk)
    const unsigned short* Bsrc0 = Bpack + (size_t)half * 25 * 512;

    // A staging: thread t handles frag-linear shorts t*4..t*4+3
    const int s = tid >> 1, j0 = (tid & 1) * 4;
    const int smp = s >> 6, sl = s & 63;
    const int srow = rb + smp * 16 + (sl & 15);
    const int sk = ((sl >> 4) * 8) + j0;
    const float* aSrc = embed + (size_t)srow * 1024 + sk;

    f32x4 acc[13];
#pragma unroll
    for (int i = 0; i < 13; ++i) acc[i] = f32x4{0.f, 0.f, 0.f, 0.f};

    // ---- prologue: stage kk=0 into buf0
    {
#pragma unroll
        for (int i = 0; i < 4; ++i) {
            const int base = i * 512 + w * 64;       // wave-uniform
            if (base < 1600)
                gload_lds16(Bsrc0 + (size_t)(base + l) * 8, &Bb[0][base * 8]);
        }
        f32x4 a0 = *(const f32x4*)(aSrc);
        unsigned int w0 = (unsigned int)f2bf(a0[0]) | ((unsigned int)f2bf(a0[1]) << 16);
        unsigned int w1 = (unsigned int)f2bf(a0[2]) | ((unsigned int)f2bf(a0[3]) << 16);
        *(unsigned int*)&Ab[0][tid * 4]     = w0;
        *(unsigned int*)&Ab[0][tid * 4 + 2] = w1;
    }
    __syncthreads();

    // ---- main loop
    int cur = 0;
    for (int kk = 0; kk < 32; ++kk) {
        const int nxt = cur ^ 1;
        const bool pf = (kk < 31);
        f32x4 an = f32x4{0.f, 0.f, 0.f, 0.f};
        if (pf) {
            const unsigned short* bs = Bsrc0 + (size_t)(kk + 1) * 50 * 512;
#pragma unroll
            for (int i = 0; i < 4; ++i) {
                const int base = i * 512 + w * 64;
                if (base < 1600)
                    gload_lds16(bs + (size_t)(base + l) * 8, &Bb[nxt][base * 8]);
            }
            an = *(const f32x4*)(aSrc + (size_t)(kk + 1) * 32);
        }

        // compute from cur buffers
        bf16x8 af = __builtin_bit_cast(bf16x8, *(const short8*)&Ab[cur][(mp * 64 + l) * 8]);
#pragma unroll
        for (int i = 0; i < 13; ++i) if (i < nn) {
            bf16x8 b = __builtin_bit_cast(bf16x8, *(const short8*)&Bb[cur][(tb + i) * 512 + l * 8]);
            acc[i] = __builtin_amdgcn_mfma_f32_16x16x32_bf16(af, b, acc[i], 0, 0, 0);
        }

        if (pf) {
            unsigned int w0 = (unsigned int)f2bf(an[0]) | ((unsigned int)f2bf(an[1]) << 16);
            unsigned int w1 = (unsigned int)f2bf(an[2]) | ((unsigned int)f2bf(an[3]) << 16);
            *(unsigned int*)&Ab[nxt][tid * 4]     = w0;
            *(unsigned int*)&Ab[nxt][tid * 4 + 2] = w1;
        }
        __syncthreads();     // drains vmcnt (B prefetch) + lgkm (A writes)
        cur = nxt;
    }

    // ---- epilogue: bias + action(K=6) contribution, store bf16
    const int rbase = rb + mp * 16 + hi * 4;
    float av[4][6];
#pragma unroll
    for (int r = 0; r < 4; ++r)
#pragma unroll
        for (int k = 0; k < 6; ++k) av[r][k] = action[(size_t)(rbase + r) * 6 + k];
#pragma unroll
    for (int i = 0; i < 13; ++i) if (i < nn) {
        const int col = (half * 25 + tb + i) * 16 + lo;
        const float bias = (col < 600) ? b_ih[col] : bq1[col - 600];
        float wa[6];
        if (col < 600) {
#pragma unroll
            for (int k = 0; k < 6; ++k) wa[k] = W_ih[k * 600 + col];
        }
#pragma unroll
        for (int r = 0; r < 4; ++r) {
            float v = acc[i][r] + bias;
            if (col < 600) {
#pragma unroll
                for (int k = 0; k < 6; ++k) v += av[r][k] * wa[k];
            }
            GI[(size_t)(rbase + r) * 800 + col] = f2bf(v);
        }
    }
}

// ---------------- kernel 2: GRU-only sequential scan ----------------
// 64 blocks x 832 thr (13 waves). Wave w owns s-tile w (cols w*16..+15), all
// 3 gates. W_hh fragments preloaded in registers; GI prefetched 1 step ahead.
#define HSTRB 232   // LDS row stride in bf16 elems (K pad >=224)

__global__ __launch_bounds__(832, 1) void k2_scan(
    unsigned short* __restrict__ GI,           // [51200][800] bf16 (deter -> cols 0..199)
    const unsigned short* __restrict__ Whh_p,
    const float* __restrict__ b_hh,
    float* __restrict__ out)                   // [51200][350] fp32 (cols 0..199 here)
{
    __shared__ unsigned short hS[16 * HSTRB];  // bf16 h, K-pad zeroed

    const int tid = threadIdx.x;
    const int w = tid >> 6, l = tid & 63;
    const int lo = l & 15, hi = l >> 4;
    const int r0 = blockIdx.x * 16;
    const int c = w * 16 + lo;                 // this thread's gate column
    const bool act = (c < 200);

    for (int i = tid; i < 16 * HSTRB; i += 832) hS[i] = 0;
    __syncthreads();

    // preload W_hh fragments: 3 gates x 7 k-slices (84 VGPR, live all 50 steps)
    bf16x8 wf[3][7];
#pragma unroll
    for (int g = 0; g < 3; ++g)
#pragma unroll
        for (int kk = 0; kk < 7; ++kk)
            wf[g][kk] = __builtin_bit_cast(bf16x8,
                *(const short8*)&Whh_p[((kk * 39 + g * 13 + w) * 64 + l) * 8]);

    float bh0 = 0.f, bh1 = 0.f, bh2 = 0.f;
    if (act) { bh0 = b_hh[c]; bh1 = b_hh[200 + c]; bh2 = b_hh[400 + c]; }
    float h_reg[4] = {0.f, 0.f, 0.f, 0.f};

    // prefetch GI gate inputs for t=0
    float cr[4], cz[4], cn[4];
    if (act) {
#pragma unroll
        for (int r = 0; r < 4; ++r) {
            const size_t gib = (size_t)((r0 + hi * 4 + r) * 50 + 0) * 800;
            cr[r] = bf2f(GI[gib + c]);
            cz[r] = bf2f(GI[gib + 200 + c]);
            cn[r] = bf2f(GI[gib + 400 + c]);
        }
    }

    for (int t = 0; t < 50; ++t) {
        // issue prefetch for t+1 (independent of everything below)
        float nr[4], nz[4], nx[4];
        const int tn = (t < 49) ? t + 1 : 49;
        if (act) {
#pragma unroll
            for (int r = 0; r < 4; ++r) {
                const size_t gib = (size_t)((r0 + hi * 4 + r) * 50 + tn) * 800;
                nr[r] = bf2f(GI[gib + c]);
                nz[r] = bf2f(GI[gib + 200 + c]);
                nx[r] = bf2f(GI[gib + 400 + c]);
            }
        }

        // A-fragments of h (bf16 direct from LDS)
        bf16x8 hf[7];
#pragma unroll
        for (int kk = 0; kk < 7; ++kk)
            hf[kk] = __builtin_bit_cast(bf16x8,
                *(const short8*)&hS[lo * HSTRB + kk * 32 + hi * 8]);

        // gh = h @ W_hh : 3 gates x 1 s-tile per wave (21 MFMA, regs only)
        f32x4 acc[3];
#pragma unroll
        for (int g = 0; g < 3; ++g) acc[g] = f32x4{0.f, 0.f, 0.f, 0.f};
#pragma unroll
        for (int g = 0; g < 3; ++g)
#pragma unroll
            for (int kk = 0; kk < 7; ++kk)
                acc[g] = __builtin_amdgcn_mfma_f32_16x16x32_bf16(hf[kk], wf[g][kk], acc[g], 0, 0, 0);

        float hnew[4];
        if (act) {
#pragma unroll
            for (int r = 0; r < 4; ++r) {
                const float gr = cr[r] + acc[0][r] + bh0;
                const float gz = cz[r] + acc[1][r] + bh1;
                const float hn = acc[2][r] + bh2;
                const float rr = 1.f / (1.f + __expf(-gr));
                const float zz = 1.f / (1.f + __expf(-gz));
                const float tt = tanhf(cn[r] + rr * hn);
                hnew[r] = (1.f - zz) * tt + zz * h_reg[r];
            }
        }
        __syncthreads();                       // B1: all hS reads of step t done
        if (act) {
#pragma unroll
            for (int r = 0; r < 4; ++r) {
                const int row = hi * 4 + r;
                const size_t bt = (size_t)((r0 + row) * 50 + t);
                h_reg[r] = hnew[r];
                hS[row * HSTRB + c] = f2bf(hnew[r]);
                out[bt * 350 + c] = hnew[r];               // deter fp32
                GI[bt * 800 + c]  = f2bf(hnew[r]);         // deter bf16 for k3
            }
        }
        __syncthreads();                       // B2: h' visible
#pragma unroll
        for (int r = 0; r < 4; ++r) { cr[r] = nr[r]; cz[r] = nz[r]; cn[r] = nx[r]; }
    }
}

// ---------------- kernel 3: heads, fully parallel over 51200 rows ----------------
__global__ __launch_bounds__(256, 1) void k3_heads(
    const unsigned short* __restrict__ GI,     // deter bf16 cols 0..199, QE cols 600..799
    const unsigned short* __restrict__ Wpq1,
    const unsigned short* __restrict__ Wpq2,
    const float* __restrict__ noise,           // [51200][30]
    const float* __restrict__ bp1,
    const float* __restrict__ bp2,
    const float* __restrict__ bq2,
    float* __restrict__ out)                   // cols 200..349
{
    __shared__ unsigned short pq[2][16 * HSTRB];  // [0]=elu prior h1, [1]=elu post h1
    __shared__ float ost[16 * 128];               // pm|ps|qm|qs raw

    const int tid = threadIdx.x;
    const int w = tid >> 6, l = tid & 63;
    const int lo = l & 15, hi = l >> 4;
    const int r0 = blockIdx.x * 16;

    {   unsigned short* p0 = &pq[0][0];
        for (int i = tid; i < 2 * 16 * HSTRB; i += 256) p0[i] = 0; }
    __syncthreads();

    // A-fragments: deter from GI (K pad 200..223 garbage x B-zero = safe)
    bf16x8 af[7];
#pragma unroll
    for (int kk = 0; kk < 7; ++kk)
        af[kk] = __builtin_bit_cast(bf16x8,
            *(const short8*)&GI[(size_t)(r0 + lo) * 800 + kk * 32 + hi * 8]);

    // heads1: 26 N-tiles over 4 waves (7/7/6/6)
    const int h1s = (w < 2) ? 7 * w : 14 + 6 * (w - 2);
    const int h1n = (w < 2) ? 7 : 6;
    f32x4 a2[7];
#pragma unroll
    for (int i = 0; i < 7; ++i) a2[i] = f32x4{0.f, 0.f, 0.f, 0.f};
#pragma unroll
    for (int i = 0; i < 7; ++i) if (i < h1n) {
        const int nt = h1s + i;
#pragma unroll
        for (int kk = 0; kk < 7; ++kk) {
            bf16x8 b = __builtin_bit_cast(bf16x8,
                *(const short8*)&Wpq1[((kk * 26 + nt) * 64 + l) * 8]);
            a2[i] = __builtin_amdgcn_mfma_f32_16x16x32_bf16(af[kk], b, a2[i], 0, 0, 0);
        }
    }
#pragma unroll
    for (int i = 0; i < 7; ++i) if (i < h1n) {
        const int nt = h1s + i;
        const bool isq = (nt >= 13);
        const int c1 = (isq ? (nt - 13) : nt) * 16 + lo;
        if (c1 < 200) {
#pragma unroll
            for (int r = 0; r < 4; ++r) {
                const int row = hi * 4 + r;
                float v = a2[i][r];
                if (isq) v += bf2f(GI[(size_t)(r0 + row) * 800 + 600 + c1]);  // QE (incl bq1)
                else     v += bp1[c1];
                v = (v > 0.f) ? v : expm1f(v);                                 // ELU
                pq[isq ? 1 : 0][row * HSTRB + c1] = f2bf(v);
            }
        }
    }
    __syncthreads();

    // heads2: waves 0,1 -> prior (tiles 0..3); waves 2,3 -> posterior (tiles 4..7)
    const unsigned short* srcS = &pq[(w >= 2) ? 1 : 0][0];
    bf16x8 pf[7];
#pragma unroll
    for (int kk = 0; kk < 7; ++kk)
        pf[kk] = __builtin_bit_cast(bf16x8,
            *(const short8*)&srcS[lo * HSTRB + kk * 32 + hi * 8]);
    f32x4 a3[2];
    a3[0] = f32x4{0.f, 0.f, 0.f, 0.f};
    a3[1] = f32x4{0.f, 0.f, 0.f, 0.f};
#pragma unroll
    for (int i = 0; i < 2; ++i) {
        const int nt = ((w >= 2) ? 4 : 0) + (w & 1) * 2 + i;
#pragma unroll
        for (int kk = 0; kk < 7; ++kk) {
            bf16x8 b = __builtin_bit_cast(bf16x8,
                *(const short8*)&Wpq2[((kk * 8 + nt) * 64 + l) * 8]);
            a3[i] = __builtin_amdgcn_mfma_f32_16x16x32_bf16(pf[kk], b, a3[i], 0, 0, 0);
        }
    }
#pragma unroll
    for (int i = 0; i < 2; ++i) {
        const int nt = ((w >= 2) ? 4 : 0) + (w & 1) * 2 + i;
        const int cl = (nt & 3) * 16 + lo;
        if (cl < 60) {
            const float bb = (nt < 4) ? bp2[cl] : bq2[cl];
            const int obase = ((nt < 4) ? 0 : 64) + ((cl < 30) ? cl : (32 + cl - 30));
#pragma unroll
            for (int r = 0; r < 4; ++r)
                ost[(hi * 4 + r) * 128 + obase] = a3[i][r] + bb;
        }
    }
    __syncthreads();

    // pack cols 200..349
    for (int idx = tid; idx < 16 * 150; idx += 256) {
        const int row = idx / 150;
        const int c = 200 + (idx - row * 150);
        const size_t bt = (size_t)(r0 + row);
        const float* o = &ost[row * 128];
        float v;
        if (c < 230) {
            const int j = c - 200;
            const float qs = softplusf(o[96 + j]) + 0.1f;
            v = o[64 + j] + qs * noise[bt * 30 + j];
        }
        else if (c < 260) v = o[c - 230];
        else if (c < 290) v = softplusf(o[32 + (c - 260)]) + 0.1f;
        else if (c < 320) v = o[64 + (c - 290)];
        else              v = softplusf(o[96 + (c - 320)]) + 0.1f;
        out[bt * 350 + c] = v;
    }
}

// ---------------------------------------------------------------------------
extern "C" void kernel_launch(void* const* d_in, const int* in_sizes, int n_in,
                              void* d_out, int out_size, void* d_ws, size_t ws_size,
                              hipStream_t stream)
{
    const float* action = (const float*)d_in[0];
    const float* embed  = (const float*)d_in[1];
    const float* noise  = (const float*)d_in[2];
    const float* W_ih   = (const float*)d_in[3];
    const float* W_hh   = (const float*)d_in[4];
    const float* b_ih   = (const float*)d_in[5];
    const float* b_hh   = (const float*)d_in[6];
    const float* Wp1    = (const float*)d_in[7];
    const float* bp1    = (const float*)d_in[8];
    const float* Wp2    = (const float*)d_in[9];
    const float* bp2    = (const float*)d_in[10];
    const float* Wq1    = (const float*)d_in[11];
    const float* bq1    = (const float*)d_in[12];
    const float* Wq2    = (const float*)d_in[13];
    const float* bq2    = (const float*)d_in[14];
    (void)in_sizes; (void)n_in; (void)out_size; (void)ws_size;

    char* ws = (char*)d_ws;
    unsigned short* GI    = (unsigned short*)(ws);
    unsigned short* Bpack = (unsigned short*)(ws + OFF_BPACK);
    unsigned short* Whh_p = (unsigned short*)(ws + OFF_WHH);
    unsigned short* Wpq1  = (unsigned short*)(ws + OFF_WPQ1);
    unsigned short* Wpq2  = (unsigned short*)(ws + OFF_WPQ2);
    float* outp = (float*)d_out;

    pack_kernel<<<4222, 256, 0, stream>>>(W_ih, W_hh, Wp1, Wq1, Wp2, Wq2,
                                          Bpack, Whh_p, Wpq1, Wpq2);
    k1_gi<<<1600, 512, 0, stream>>>(embed, action, W_ih, b_ih, bq1, Bpack, GI);
    k2_scan<<<64, 832, 0, stream>>>(GI, Whh_p, b_hh, outp);
    k3_heads<<<3200, 256, 0, stream>>>(GI, Wpq1, Wpq2, noise, bp1, bp2, bq2, outp);
}

// Round 7
// 447.434 us; speedup vs baseline: 1.8481x; 1.4926x over previous
//
#include <hip/hip_runtime.h>
#include <hip/hip_bf16.h>
#include <cstdint>

// ---------------------------------------------------------------------------
// WorldModel RSSM: B=1024 T=50 E=1024 A=6 S=200 H=200 L=30
// fp32 in/out; internal GEMMs bf16 MFMA w/ fp32 accum.
//
//   k1: GI[bt,0:600]=concat(a,e)@W_ih+b_ih ; GI[bt,600:800]=e@Wq1[200:]+bq1
//       2-phase double-buffered LDS pipeline (unchanged from round 6).
//   k2: GRU scan, 64 blocks x 8 waves. W_hh frags RESIDENT in regs
//       (140 VGPR/wave, fits 256-cap at 2 waves/SIMD); gate pre-activations
//       exchanged via LDS gAll; GI streamed via global_load_lds dbuf with
//       counted vmcnt; raw lgkm-only barriers (stores never drain).
//   k3: heads (fc_prior/fc_posterior + softplus + rsample) fully parallel.
// ---------------------------------------------------------------------------

typedef __attribute__((ext_vector_type(8))) short   short8;
typedef __attribute__((ext_vector_type(8))) __bf16  bf16x8;
typedef __attribute__((ext_vector_type(4))) float   f32x4;

__device__ __forceinline__ float bf2f(unsigned short u) {
    unsigned int v = ((unsigned int)u) << 16;
    return __builtin_bit_cast(float, v);
}
__device__ __forceinline__ unsigned short f2bf(float f) {
    unsigned int v = __builtin_bit_cast(unsigned int, f);
    v = v + 0x7FFFu + ((v >> 16) & 1u);   // RNE
    return (unsigned short)(v >> 16);
}
__device__ __forceinline__ float softplusf(float x) {
    return (x > 20.f) ? x : log1pf(__expf(x));
}
__device__ __forceinline__ void gload_lds16(const void* g, void* l) {
    __builtin_amdgcn_global_load_lds(
        (const __attribute__((address_space(1))) void*)g,
        (__attribute__((address_space(3))) void*)l, 16, 0, 0);
}

// ---------------- workspace layout (bytes) ----------------
#define OFF_BPACK 81920000
#define OFF_WHH   83558400
#define OFF_WPQ1  83837952
#define OFF_WPQ2  84024320

// fragment mapping (mfma_f32_16x16x32_bf16):
//   A[l&15][(l>>4)*8+j], B[(l>>4)*8+j][l&15], D[(l>>4)*4+r][l&15]
// packed B storage: elem = ((kk*NT + nt)*64 + l)*8 + j

__global__ __launch_bounds__(256) void pack_kernel(
    const float* __restrict__ W_ih, const float* __restrict__ W_hh,
    const float* __restrict__ Wp1,  const float* __restrict__ Wq1,
    const float* __restrict__ Wp2,  const float* __restrict__ Wq2,
    unsigned short* __restrict__ Bpack, unsigned short* __restrict__ Whh_p,
    unsigned short* __restrict__ Wpq1,  unsigned short* __restrict__ Wpq2)
{
    int e = blockIdx.x * 256 + threadIdx.x;
    if (e < 819200) {                       // k1: K=1024(embed), N=800
        const int j = e & 7, l = (e >> 3) & 63;
        const int nt = (e >> 9) % 50, kk = e / (512 * 50);
        const int k = kk * 32 + (l >> 4) * 8 + j;
        const int c = nt * 16 + (l & 15);
        Bpack[e] = f2bf((c < 600) ? W_ih[(6 + k) * 600 + c]
                                  : Wq1[(200 + k) * 200 + (c - 600)]);
        return;
    }
    e -= 819200;
    if (e < 139776) {                       // W_hh: K pad 224, N = 3 gates x 13 tiles
        const int j = e & 7, l = (e >> 3) & 63;
        const int nt = (e >> 9) % 39, kk = e / (512 * 39);
        const int k = kk * 32 + (l >> 4) * 8 + j;
        const int g = nt / 13, st = nt % 13;
        const int c = st * 16 + (l & 15);
        Whh_p[e] = (k < 200 && c < 200) ? f2bf(W_hh[k * 600 + g * 200 + c]) : (unsigned short)0;
        return;
    }
    e -= 139776;
    if (e < 93184) {                        // heads1: [Wp1 | Wq1[:200]] K pad 224
        const int j = e & 7, l = (e >> 3) & 63;
        const int nt = (e >> 9) % 26, kk = e / (512 * 26);
        const int k = kk * 32 + (l >> 4) * 8 + j;
        unsigned short v = 0;
        if (nt < 13) { const int c = nt * 16 + (l & 15);        if (k < 200 && c < 200) v = f2bf(Wp1[k * 200 + c]); }
        else         { const int c = (nt - 13) * 16 + (l & 15); if (k < 200 && c < 200) v = f2bf(Wq1[k * 200 + c]); }
        Wpq1[e] = v;
        return;
    }
    e -= 93184;
    if (e < 28672) {                        // heads2: [Wp2 | Wq2] N pad 64 each
        const int j = e & 7, l = (e >> 3) & 63;
        const int nt = (e >> 9) % 8, kk = e / (512 * 8);
        const int k = kk * 32 + (l >> 4) * 8 + j;
        unsigned short v = 0;
        if (nt < 4) { const int c = nt * 16 + (l & 15);       if (k < 200 && c < 60) v = f2bf(Wp2[k * 60 + c]); }
        else        { const int c = (nt - 4) * 16 + (l & 15); if (k < 200 && c < 60) v = f2bf(Wq2[k * 60 + c]); }
        Wpq2[e] = v;
    }
}

// ---------------- kernel 1: GI/QE GEMM  M=51200 N=800 K=1024 ----------------
__global__ __launch_bounds__(512, 4) void k1_gi(
    const float* __restrict__ embed,   // [51200][1024]
    const float* __restrict__ action,  // [51200][6]
    const float* __restrict__ W_ih,    // rows 0..5 = action part
    const float* __restrict__ b_ih,
    const float* __restrict__ bq1,
    const unsigned short* __restrict__ Bpack,
    unsigned short* __restrict__ GI)   // [51200][800] bf16
{
    __shared__ unsigned short Bb[2][12800];   // 25 tiles x 512 shorts, dbuf
    __shared__ unsigned short Ab[2][2048];    // 4 mp-frags x 512 shorts, dbuf

    const int tid = threadIdx.x;
    const int w = tid >> 6, l = tid & 63;
    const int lo = l & 15, hi = l >> 4;
    const int mp = w >> 1, nq = w & 1;
    const int mblk = blockIdx.x >> 1;          // 0..799
    const int half = blockIdx.x & 1;           // 0..1
    const int tb = nq * 13;                    // local tile base (0 or 13)
    const int nn = nq ? 12 : 13;
    const int rb = mblk * 64;

    const unsigned short* Bsrc0 = Bpack + (size_t)half * 25 * 512;

    const int s = tid >> 1, j0 = (tid & 1) * 4;
    const int smp = s >> 6, sl = s & 63;
    const int srow = rb + smp * 16 + (sl & 15);
    const int sk = ((sl >> 4) * 8) + j0;
    const float* aSrc = embed + (size_t)srow * 1024 + sk;

    f32x4 acc[13];
#pragma unroll
    for (int i = 0; i < 13; ++i) acc[i] = f32x4{0.f, 0.f, 0.f, 0.f};

    {
#pragma unroll
        for (int i = 0; i < 4; ++i) {
            const int base = i * 512 + w * 64;       // wave-uniform
            if (base < 1600)
                gload_lds16(Bsrc0 + (size_t)(base + l) * 8, &Bb[0][base * 8]);
        }
        f32x4 a0 = *(const f32x4*)(aSrc);
        unsigned int w0 = (unsigned int)f2bf(a0[0]) | ((unsigned int)f2bf(a0[1]) << 16);
        unsigned int w1 = (unsigned int)f2bf(a0[2]) | ((unsigned int)f2bf(a0[3]) << 16);
        *(unsigned int*)&Ab[0][tid * 4]     = w0;
        *(unsigned int*)&Ab[0][tid * 4 + 2] = w1;
    }
    __syncthreads();

    int cur = 0;
    for (int kk = 0; kk < 32; ++kk) {
        const int nxt = cur ^ 1;
        const bool pf = (kk < 31);
        f32x4 an = f32x4{0.f, 0.f, 0.f, 0.f};
        if (pf) {
            const unsigned short* bs = Bsrc0 + (size_t)(kk + 1) * 50 * 512;
#pragma unroll
            for (int i = 0; i < 4; ++i) {
                const int base = i * 512 + w * 64;
                if (base < 1600)
                    gload_lds16(bs + (size_t)(base + l) * 8, &Bb[nxt][base * 8]);
            }
            an = *(const f32x4*)(aSrc + (size_t)(kk + 1) * 32);
        }

        bf16x8 af = __builtin_bit_cast(bf16x8, *(const short8*)&Ab[cur][(mp * 64 + l) * 8]);
#pragma unroll
        for (int i = 0; i < 13; ++i) if (i < nn) {
            bf16x8 b = __builtin_bit_cast(bf16x8, *(const short8*)&Bb[cur][(tb + i) * 512 + l * 8]);
            acc[i] = __builtin_amdgcn_mfma_f32_16x16x32_bf16(af, b, acc[i], 0, 0, 0);
        }

        if (pf) {
            unsigned int w0 = (unsigned int)f2bf(an[0]) | ((unsigned int)f2bf(an[1]) << 16);
            unsigned int w1 = (unsigned int)f2bf(an[2]) | ((unsigned int)f2bf(an[3]) << 16);
            *(unsigned int*)&Ab[nxt][tid * 4]     = w0;
            *(unsigned int*)&Ab[nxt][tid * 4 + 2] = w1;
        }
        __syncthreads();
        cur = nxt;
    }

    const int rbase = rb + mp * 16 + hi * 4;
    float av[4][6];
#pragma unroll
    for (int r = 0; r < 4; ++r)
#pragma unroll
        for (int k = 0; k < 6; ++k) av[r][k] = action[(size_t)(rbase + r) * 6 + k];
#pragma unroll
    for (int i = 0; i < 13; ++i) if (i < nn) {
        const int col = (half * 25 + tb + i) * 16 + lo;
        const float bias = (col < 600) ? b_ih[col] : bq1[col - 600];
        float wa[6];
        if (col < 600) {
#pragma unroll
            for (int k = 0; k < 6; ++k) wa[k] = W_ih[k * 600 + col];
        }
#pragma unroll
        for (int r = 0; r < 4; ++r) {
            float v = acc[i][r] + bias;
            if (col < 600) {
#pragma unroll
                for (int k = 0; k < 6; ++k) v += av[r][k] * wa[k];
            }
            GI[(size_t)(rbase + r) * 800 + col] = f2bf(v);
        }
    }
}

// ---------------- kernel 2: GRU scan, 8 waves, resident weights ----------------
// 64 blocks x 512 thr. Wave w owns gate-tiles 5w..5w+4 (wave7: 4); MFMA results
// exchanged via LDS gAll; gate compute mapped thread->(col=tid&255, 8 rows).
// GI gate inputs: global_load_lds dbuf gather (3 issues/wave/step, vmcnt(3)).
#define HSTRB 232   // hS row stride in bf16 elems (K pad >=224)
#define GSTR  227   // gAll row stride in floats (odd-ish vs 32 banks)

__global__ __launch_bounds__(512, 2) void k2_scan(
    unsigned short* __restrict__ GI,           // [51200][800] bf16 (deter -> cols 0..199)
    const unsigned short* __restrict__ Whh_p,
    const float* __restrict__ b_hh,
    float* __restrict__ out)                   // [51200][350] fp32 (cols 0..199 here)
{
    __shared__ unsigned short hS[16 * HSTRB];                 // 7424 B, bf16 h
    __shared__ float gAll[3 * 16 * GSTR];                     // 43584 B
    __shared__ __align__(16) unsigned short GIbuf[2][12288];  // 49152 B (1536 chunks x 16B)

    const int tid = threadIdx.x;
    const int w = tid >> 6, l = tid & 63;
    const int lo = l & 15, hi = l >> 4;
    const int r0 = blockIdx.x * 16;

    for (int i = tid; i < 16 * HSTRB; i += 512) hS[i] = 0;

    // ---- resident W_hh fragments: 5 tiles x 7 k-slices (140 VGPR)
    const int t0 = w * 5;
    const int ntl = (w == 7) ? 4 : 5;
    bf16x8 wf[5][7];
#pragma unroll
    for (int i = 0; i < 5; ++i)
#pragma unroll
        for (int kk = 0; kk < 7; ++kk)
            if (i < ntl)
                wf[i][kk] = __builtin_bit_cast(bf16x8,
                    *(const short8*)&Whh_p[((kk * 39 + (t0 + i)) * 64 + l) * 8]);

    // gAll write offsets per tile (D: row=hi*4+r, col=st*16+lo)
    int gOff[5];
#pragma unroll
    for (int i = 0; i < 5; ++i) {
        int nt = t0 + i; if (nt > 38) nt = 38;
        const int g = nt / 13, st = nt - g * 13;
        gOff[i] = (g * 16 + hi * 4) * GSTR + st * 16 + lo;
    }

    // ---- GI gather source addresses (3 chunks/thread), chunk j -> (row, colchunk)
    const char* srcB[3];
#pragma unroll
    for (int i = 0; i < 3; ++i) {
        int j = (i * 8 + w) * 64 + l;
        int rj = j / 75; int cj = j - rj * 75;
        if (rj > 15) { rj = 15; cj = 74; }
        srcB[i] = (const char*)GI + (size_t)(r0 + rj) * 50 * 1600 + (size_t)cj * 16;
    }

    // ---- gate-phase mapping: col c, rows rh*8..rh*8+7
    const int c = tid & 255;
    const int rh = tid >> 8;
    const bool act = (c < 200);
    float bh0 = 0.f, bh1 = 0.f, bh2 = 0.f;
    if (act) { bh0 = b_hh[c]; bh1 = b_hh[200 + c]; bh2 = b_hh[400 + c]; }
    float h_reg[8] = {0.f, 0.f, 0.f, 0.f, 0.f, 0.f, 0.f, 0.f};

    // ---- prologue: gather t=0 into buf0; hS zeros visible
    {
#pragma unroll
        for (int i = 0; i < 3; ++i)
            gload_lds16(srcB[i], &GIbuf[0][(i * 8 + w) * 512]);
    }
    asm volatile("s_waitcnt lgkmcnt(0)" ::: "memory");
    __builtin_amdgcn_s_barrier();
    __builtin_amdgcn_sched_barrier(0);

    for (int t = 0; t < 50; ++t) {
        // A) issue gather for t+1 (stays in flight across barriers)
        const int tn = (t < 49) ? t + 1 : 49;
        const int bsel = (t + 1) & 1;
#pragma unroll
        for (int i = 0; i < 3; ++i)
            gload_lds16(srcB[i] + (size_t)tn * 1600, &GIbuf[bsel][(i * 8 + w) * 512]);

        // B) MFMA phase: hf from hS, 5 chains x 7 into acc
        bf16x8 hf[7];
#pragma unroll
        for (int kk = 0; kk < 7; ++kk)
            hf[kk] = __builtin_bit_cast(bf16x8,
                *(const short8*)&hS[lo * HSTRB + kk * 32 + hi * 8]);
        f32x4 acc[5];
#pragma unroll
        for (int i = 0; i < 5; ++i) acc[i] = f32x4{0.f, 0.f, 0.f, 0.f};
#pragma unroll
        for (int i = 0; i < 5; ++i) if (i < ntl)
#pragma unroll
            for (int kk = 0; kk < 7; ++kk)
                acc[i] = __builtin_amdgcn_mfma_f32_16x16x32_bf16(hf[kk], wf[i][kk], acc[i], 0, 0, 0);

        // C) publish pre-activations
#pragma unroll
        for (int i = 0; i < 5; ++i) if (i < ntl)
#pragma unroll
            for (int r = 0; r < 4; ++r)
                gAll[gOff[i] + r * GSTR] = acc[i][r];

        asm volatile("s_waitcnt lgkmcnt(0)" ::: "memory");   // B1: gAll + hS reads done
        __builtin_amdgcn_s_barrier();
        __builtin_amdgcn_sched_barrier(0);
        asm volatile("s_waitcnt vmcnt(3)" ::: "memory");     // GIbuf[t&1] ready
        __builtin_amdgcn_sched_barrier(0);

        // D) gate phase
        if (act) {
            const unsigned short* gib = &GIbuf[t & 1][0];
#pragma unroll
            for (int rr = 0; rr < 8; ++rr) {
                const int row = rh * 8 + rr;
                const float gi_r = bf2f(gib[row * 600 + c]);
                const float gi_z = bf2f(gib[row * 600 + 200 + c]);
                const float gi_n = bf2f(gib[row * 600 + 400 + c]);
                const float gr = gi_r + gAll[(0 * 16 + row) * GSTR + c] + bh0;
                const float gz = gi_z + gAll[(1 * 16 + row) * GSTR + c] + bh1;
                const float hn = gAll[(2 * 16 + row) * GSTR + c] + bh2;
                const float rs = __builtin_amdgcn_rcpf(1.f + __expf(-gr));
                const float zz = __builtin_amdgcn_rcpf(1.f + __expf(-gz));
                const float x  = gi_n + rs * hn;
                const float e2 = __expf(-2.f * fabsf(x));
                float th = (1.f - e2) * __builtin_amdgcn_rcpf(1.f + e2);
                th = __builtin_copysignf(th, x);
                const float h = (1.f - zz) * th + zz * h_reg[rr];
                h_reg[rr] = h;
                hS[row * HSTRB + c] = f2bf(h);
                const size_t bt = (size_t)((r0 + row) * 50 + t);
                out[bt * 350 + c] = h;                 // deter fp32
                GI[bt * 800 + c]  = f2bf(h);           // deter bf16 for k3
            }
        }

        asm volatile("s_waitcnt lgkmcnt(0)" ::: "memory");   // B2: h' visible
        __builtin_amdgcn_s_barrier();
        __builtin_amdgcn_sched_barrier(0);
    }
}

// ---------------- kernel 3: heads, fully parallel over 51200 rows ----------------
__global__ __launch_bounds__(256, 1) void k3_heads(
    const unsigned short* __restrict__ GI,     // deter bf16 cols 0..199, QE cols 600..799
    const unsigned short* __restrict__ Wpq1,
    const unsigned short* __restrict__ Wpq2,
    const float* __restrict__ noise,           // [51200][30]
    const float* __restrict__ bp1,
    const float* __restrict__ bp2,
    const float* __restrict__ bq2,
    float* __restrict__ out)                   // cols 200..349
{
    __shared__ unsigned short pq[2][16 * HSTRB];  // [0]=elu prior h1, [1]=elu post h1
    __shared__ float ost[16 * 128];               // pm|ps|qm|qs raw

    const int tid = threadIdx.x;
    const int w = tid >> 6, l = tid & 63;
    const int lo = l & 15, hi = l >> 4;
    const int r0 = blockIdx.x * 16;

    {   unsigned short* p0 = &pq[0][0];
        for (int i = tid; i < 2 * 16 * HSTRB; i += 256) p0[i] = 0; }
    __syncthreads();

    bf16x8 af[7];
#pragma unroll
    for (int kk = 0; kk < 7; ++kk)
        af[kk] = __builtin_bit_cast(bf16x8,
            *(const short8*)&GI[(size_t)(r0 + lo) * 800 + kk * 32 + hi * 8]);

    const int h1s = (w < 2) ? 7 * w : 14 + 6 * (w - 2);
    const int h1n = (w < 2) ? 7 : 6;
    f32x4 a2[7];
#pragma unroll
    for (int i = 0; i < 7; ++i) a2[i] = f32x4{0.f, 0.f, 0.f, 0.f};
#pragma unroll
    for (int i = 0; i < 7; ++i) if (i < h1n) {
        const int nt = h1s + i;
#pragma unroll
        for (int kk = 0; kk < 7; ++kk) {
            bf16x8 b = __builtin_bit_cast(bf16x8,
                *(const short8*)&Wpq1[((kk * 26 + nt) * 64 + l) * 8]);
            a2[i] = __builtin_amdgcn_mfma_f32_16x16x32_bf16(af[kk], b, a2[i], 0, 0, 0);
        }
    }
#pragma unroll
    for (int i = 0; i < 7; ++i) if (i < h1n) {
        const int nt = h1s + i;
        const bool isq = (nt >= 13);
        const int c1 = (isq ? (nt - 13) : nt) * 16 + lo;
        if (c1 < 200) {
#pragma unroll
            for (int r = 0; r < 4; ++r) {
                const int row = hi * 4 + r;
                float v = a2[i][r];
                if (isq) v += bf2f(GI[(size_t)(r0 + row) * 800 + 600 + c1]);  // QE (incl bq1)
                else     v += bp1[c1];
                v = (v > 0.f) ? v : expm1f(v);                                 // ELU
                pq[isq ? 1 : 0][row * HSTRB + c1] = f2bf(v);
            }
        }
    }
    __syncthreads();

    const unsigned short* srcS = &pq[(w >= 2) ? 1 : 0][0];
    bf16x8 pf[7];
#pragma unroll
    for (int kk = 0; kk < 7; ++kk)
        pf[kk] = __builtin_bit_cast(bf16x8,
            *(const short8*)&srcS[lo * HSTRB + kk * 32 + hi * 8]);
    f32x4 a3[2];
    a3[0] = f32x4{0.f, 0.f, 0.f, 0.f};
    a3[1] = f32x4{0.f, 0.f, 0.f, 0.f};
#pragma unroll
    for (int i = 0; i < 2; ++i) {
        const int nt = ((w >= 2) ? 4 : 0) + (w & 1) * 2 + i;
#pragma unroll
        for (int kk = 0; kk < 7; ++kk) {
            bf16x8 b = __builtin_bit_cast(bf16x8,
                *(const short8*)&Wpq2[((kk * 8 + nt) * 64 + l) * 8]);
            a3[i] = __builtin_amdgcn_mfma_f32_16x16x32_bf16(pf[kk], b, a3[i], 0, 0, 0);
        }
    }
#pragma unroll
    for (int i = 0; i < 2; ++i) {
        const int nt = ((w >= 2) ? 4 : 0) + (w & 1) * 2 + i;
        const int cl = (nt & 3) * 16 + lo;
        if (cl < 60) {
            const float bb = (nt < 4) ? bp2[cl] : bq2[cl];
            const int obase = ((nt < 4) ? 0 : 64) + ((cl < 30) ? cl : (32 + cl - 30));
#pragma unroll
            for (int r = 0; r < 4; ++r)
                ost[(hi * 4 + r) * 128 + obase] = a3[i][r] + bb;
        }
    }
    __syncthreads();

    for (int idx = tid; idx < 16 * 150; idx += 256) {
        const int row = idx / 150;
        const int c = 200 + (idx - row * 150);
        const size_t bt = (size_t)(r0 + row);
        const float* o = &ost[row * 128];
        float v;
        if (c < 230) {
            const int j = c - 200;
            const float qs = softplusf(o[96 + j]) + 0.1f;
            v = o[64 + j] + qs * noise[bt * 30 + j];
        }
        else if (c < 260) v = o[c - 230];
        else if (c < 290) v = softplusf(o[32 + (c - 260)]) + 0.1f;
        else if (c < 320) v = o[64 + (c - 290)];
        else              v = softplusf(o[96 + (c - 320)]) + 0.1f;
        out[bt * 350 + c] = v;
    }
}

// ---------------------------------------------------------------------------
extern "C" void kernel_launch(void* const* d_in, const int* in_sizes, int n_in,
                              void* d_out, int out_size, void* d_ws, size_t ws_size,
                              hipStream_t stream)
{
    const float* action = (const float*)d_in[0];
    const float* embed  = (const float*)d_in[1];
    const float* noise  = (const float*)d_in[2];
    const float* W_ih   = (const float*)d_in[3];
    const float* W_hh   = (const float*)d_in[4];
    const float* b_ih   = (const float*)d_in[5];
    const float* b_hh   = (const float*)d_in[6];
    const float* Wp1    = (const float*)d_in[7];
    const float* bp1    = (const float*)d_in[8];
    const float* Wp2    = (const float*)d_in[9];
    const float* bp2    = (const float*)d_in[10];
    const float* Wq1    = (const float*)d_in[11];
    const float* bq1    = (const float*)d_in[12];
    const float* Wq2    = (const float*)d_in[13];
    const float* bq2    = (const float*)d_in[14];
    (void)in_sizes; (void)n_in; (void)out_size; (void)ws_size;

    char* ws = (char*)d_ws;
    unsigned short* GI    = (unsigned short*)(ws);
    unsigned short* Bpack = (unsigned short*)(ws + OFF_BPACK);
    unsigned short* Whh_p = (unsigned short*)(ws + OFF_WHH);
    unsigned short* Wpq1  = (unsigned short*)(ws + OFF_WPQ1);
    unsigned short* Wpq2  = (unsigned short*)(ws + OFF_WPQ2);
    float* outp = (float*)d_out;

    pack_kernel<<<4222, 256, 0, stream>>>(W_ih, W_hh, Wp1, Wq1, Wp2, Wq2,
                                          Bpack, Whh_p, Wpq1, Wpq2);
    k1_gi<<<1600, 512, 0, stream>>>(embed, action, W_ih, b_ih, bq1, Bpack, GI);
    k2_scan<<<64, 512, 0, stream>>>(GI, Whh_p, b_hh, outp);
    k3_heads<<<3200, 256, 0, stream>>>(GI, Wpq1, Wpq2, noise, bp1, bp2, bq2, outp);
}

// Round 8
// 419.511 us; speedup vs baseline: 1.9711x; 1.0666x over previous
//
#include <hip/hip_runtime.h>
#include <hip/hip_bf16.h>
#include <cstdint>

// ---------------------------------------------------------------------------
// WorldModel RSSM: B=1024 T=50 E=1024 A=6 S=200 H=200 L=30
// fp32 in/out; internal GEMMs bf16 MFMA w/ fp32 accum.
//
//   k1: GI[bt,0:600]=concat(a,e)@W_ih+b_ih ; GI[bt,600:800]=e@Wq1[200:]+bq1
//       m97-style: tile 128x160, ALL staging via global_load_lds (B linear,
//       A per-lane fp32 gather in fragment order), 1 barrier/K-step,
//       52KB LDS dbuf -> 3 blocks/CU. fp32->bf16 convert from LDS (VALU only).
//   k2: GRU scan, 64 blocks x 8 waves, W_hh resident in regs (round 7).
//   k3: heads (fc_prior/fc_posterior + softplus + rsample) fully parallel.
// ---------------------------------------------------------------------------

typedef __attribute__((ext_vector_type(8))) short   short8;
typedef __attribute__((ext_vector_type(8))) __bf16  bf16x8;
typedef __attribute__((ext_vector_type(4))) float   f32x4;

__device__ __forceinline__ float bf2f(unsigned short u) {
    unsigned int v = ((unsigned int)u) << 16;
    return __builtin_bit_cast(float, v);
}
__device__ __forceinline__ unsigned short f2bf(float f) {
    unsigned int v = __builtin_bit_cast(unsigned int, f);
    v = v + 0x7FFFu + ((v >> 16) & 1u);   // RNE
    return (unsigned short)(v >> 16);
}
__device__ __forceinline__ float softplusf(float x) {
    return (x > 20.f) ? x : log1pf(__expf(x));
}
__device__ __forceinline__ void gload_lds16(const void* g, void* l) {
    __builtin_amdgcn_global_load_lds(
        (const __attribute__((address_space(1))) void*)g,
        (__attribute__((address_space(3))) void*)l, 16, 0, 0);
}

// ---------------- workspace layout (bytes) ----------------
#define OFF_BPACK 81920000
#define OFF_WHH   83558400
#define OFF_WPQ1  83837952
#define OFF_WPQ2  84024320

// fragment mapping (mfma_f32_16x16x32_bf16):
//   A[l&15][(l>>4)*8+j], B[(l>>4)*8+j][l&15], D[(l>>4)*4+r][l&15]
// packed B storage: elem = ((kk*NT + nt)*64 + l)*8 + j

__global__ __launch_bounds__(256) void pack_kernel(
    const float* __restrict__ W_ih, const float* __restrict__ W_hh,
    const float* __restrict__ Wp1,  const float* __restrict__ Wq1,
    const float* __restrict__ Wp2,  const float* __restrict__ Wq2,
    unsigned short* __restrict__ Bpack, unsigned short* __restrict__ Whh_p,
    unsigned short* __restrict__ Wpq1,  unsigned short* __restrict__ Wpq2)
{
    int e = blockIdx.x * 256 + threadIdx.x;
    if (e < 819200) {                       // k1: K=1024(embed), N=800
        const int j = e & 7, l = (e >> 3) & 63;
        const int nt = (e >> 9) % 50, kk = e / (512 * 50);
        const int k = kk * 32 + (l >> 4) * 8 + j;
        const int c = nt * 16 + (l & 15);
        Bpack[e] = f2bf((c < 600) ? W_ih[(6 + k) * 600 + c]
                                  : Wq1[(200 + k) * 200 + (c - 600)]);
        return;
    }
    e -= 819200;
    if (e < 139776) {                       // W_hh: K pad 224, N = 3 gates x 13 tiles
        const int j = e & 7, l = (e >> 3) & 63;
        const int nt = (e >> 9) % 39, kk = e / (512 * 39);
        const int k = kk * 32 + (l >> 4) * 8 + j;
        const int g = nt / 13, st = nt % 13;
        const int c = st * 16 + (l & 15);
        Whh_p[e] = (k < 200 && c < 200) ? f2bf(W_hh[k * 600 + g * 200 + c]) : (unsigned short)0;
        return;
    }
    e -= 139776;
    if (e < 93184) {                        // heads1: [Wp1 | Wq1[:200]] K pad 224
        const int j = e & 7, l = (e >> 3) & 63;
        const int nt = (e >> 9) % 26, kk = e / (512 * 26);
        const int k = kk * 32 + (l >> 4) * 8 + j;
        unsigned short v = 0;
        if (nt < 13) { const int c = nt * 16 + (l & 15);        if (k < 200 && c < 200) v = f2bf(Wp1[k * 200 + c]); }
        else         { const int c = (nt - 13) * 16 + (l & 15); if (k < 200 && c < 200) v = f2bf(Wq1[k * 200 + c]); }
        Wpq1[e] = v;
        return;
    }
    e -= 93184;
    if (e < 28672) {                        // heads2: [Wp2 | Wq2] N pad 64 each
        const int j = e & 7, l = (e >> 3) & 63;
        const int nt = (e >> 9) % 8, kk = e / (512 * 8);
        const int k = kk * 32 + (l >> 4) * 8 + j;
        unsigned short v = 0;
        if (nt < 4) { const int c = nt * 16 + (l & 15);       if (k < 200 && c < 60) v = f2bf(Wp2[k * 60 + c]); }
        else        { const int c = (nt - 4) * 16 + (l & 15); if (k < 200 && c < 60) v = f2bf(Wq2[k * 60 + c]); }
        Wpq2[e] = v;
    }
}

// ---------------- kernel 1: GI/QE GEMM  M=51200 N=800 K=1024 ----------------
// grid 2000 = 400 M-chunks(128 rows) x 5 N-groups(160 cols = 10 tiles).
// 256 thr = 4 waves; wave w -> M-subtiles {2w,2w+1} x all 10 N-tiles
// (acc[2][10] = 80 VGPR). Per K-step stage = 10KB B + 16KB A(fp32), dbuf
// 52KB -> 3 blocks/CU. Everything via global_load_lds; 1 barrier/K-step.
#define K1_BUF 13312   // shorts per buffer: B 5120 + A 8192
__global__ __launch_bounds__(256, 3) void k1_gi(
    const float* __restrict__ embed,   // [51200][1024]
    const float* __restrict__ action,  // [51200][6]
    const float* __restrict__ W_ih,    // rows 0..5 = action part
    const float* __restrict__ b_ih,
    const float* __restrict__ bq1,
    const unsigned short* __restrict__ Bpack,
    unsigned short* __restrict__ GI)   // [51200][800] bf16
{
    __shared__ short bufS[2][K1_BUF];

    const int tid = threadIdx.x;
    const int w = tid >> 6, l = tid & 63;
    const int lo = l & 15, hi = l >> 4;

    // XCD-bijective swizzle: 5 N-siblings of an M-chunk land on one XCD
    const int g    = (blockIdx.x & 7) * 250 + (blockIdx.x >> 3);
    const int mblk = g / 5;
    const int ng   = g - mblk * 5;
    const int rb   = mblk * 128;

    // ---- stage-chunk setup: 26 chunks (10 B + 16 A), wave w does j=w+4i
    const char* sp[7]; int st[7]; int dof[7]; bool en[7];
#pragma unroll
    for (int i = 0; i < 7; ++i) {
        const int j = w + 4 * i;
        en[i] = (j < 26);
        const int jc = (j < 26) ? j : 25;
        if (jc < 10) {                     // B tile jc (1KB linear)
            sp[i]  = (const char*)(Bpack + (size_t)(ng * 10 + jc) * 512 + l * 8);
            st[i]  = 50 * 512 * 2;         // 51200 B per kk
            dof[i] = jc * 512;
        } else {                           // A chunk: Msub m, half h (per-lane gather)
            const int a = jc - 10, m = a >> 1, h = a & 1;
            sp[i]  = (const char*)(embed + (size_t)(rb + m * 16 + (l & 15)) * 1024
                                         + (l >> 4) * 8 + h * 4);
            st[i]  = 32 * 4;               // 128 B per kk
            dof[i] = 5120 + a * 512;
        }
    }

    f32x4 acc[2][10];
#pragma unroll
    for (int m = 0; m < 2; ++m)
#pragma unroll
        for (int i = 0; i < 10; ++i) acc[m][i] = f32x4{0.f, 0.f, 0.f, 0.f};

    // ---- prologue: stage kk=0 -> buf0
#pragma unroll
    for (int i = 0; i < 7; ++i) if (en[i]) {
        gload_lds16(sp[i], &bufS[0][dof[i]]);
        sp[i] += st[i];
    }
    __syncthreads();

    // ---- main loop: 1 barrier per K-step
    int cur = 0;
    for (int kk = 0; kk < 32; ++kk) {
        const int nxt = cur ^ 1;
        if (kk < 31) {
#pragma unroll
            for (int i = 0; i < 7; ++i) if (en[i]) {
                gload_lds16(sp[i], &bufS[nxt][dof[i]]);
                sp[i] += st[i];
            }
        }

        // A fragments: conflict-free LDS read + fp32->bf16 convert (VALU only)
        const float* Af = (const float*)&bufS[cur][5120];
        bf16x8 af[2];
#pragma unroll
        for (int m = 0; m < 2; ++m) {
            const int ms = w * 2 + m;
            f32x4 v0 = *(const f32x4*)&Af[(ms * 2 + 0) * 256 + l * 4];
            f32x4 v1 = *(const f32x4*)&Af[(ms * 2 + 1) * 256 + l * 4];
            bf16x8 t;
#pragma unroll
            for (int q = 0; q < 4; ++q) { t[q] = (__bf16)v0[q]; t[4 + q] = (__bf16)v1[q]; }
            af[m] = t;
        }
#pragma unroll
        for (int i = 0; i < 10; ++i) {
            bf16x8 b = __builtin_bit_cast(bf16x8, *(const short8*)&bufS[cur][i * 512 + l * 8]);
            acc[0][i] = __builtin_amdgcn_mfma_f32_16x16x32_bf16(af[0], b, acc[0][i], 0, 0, 0);
            acc[1][i] = __builtin_amdgcn_mfma_f32_16x16x32_bf16(af[1], b, acc[1][i], 0, 0, 0);
        }
        __syncthreads();     // drains vmcnt (stage kk+1) + lgkm (A reads)
        cur = nxt;
    }

    // ---- epilogue: bias + action(K=6) contribution, store bf16
#pragma unroll
    for (int m = 0; m < 2; ++m) {
        const int rbase = rb + (w * 2 + m) * 16 + hi * 4;
        float av[4][6];
#pragma unroll
        for (int r = 0; r < 4; ++r)
#pragma unroll
            for (int k = 0; k < 6; ++k) av[r][k] = action[(size_t)(rbase + r) * 6 + k];
#pragma unroll
        for (int i = 0; i < 10; ++i) {
            const int col = ng * 160 + i * 16 + lo;
            const float bias = (col < 600) ? b_ih[col] : bq1[col - 600];
            float wa[6];
            if (col < 600) {
#pragma unroll
                for (int k = 0; k < 6; ++k) wa[k] = W_ih[k * 600 + col];
            }
#pragma unroll
            for (int r = 0; r < 4; ++r) {
                float v = acc[m][i][r] + bias;
                if (col < 600) {
#pragma unroll
                    for (int k = 0; k < 6; ++k) v += av[r][k] * wa[k];
                }
                GI[(size_t)(rbase + r) * 800 + col] = f2bf(v);
            }
        }
    }
}

// ---------------- kernel 2: GRU scan, 8 waves, resident weights ----------------
#define HSTRB 232   // hS row stride in bf16 elems (K pad >=224)
#define GSTR  227   // gAll row stride in floats (odd-ish vs 32 banks)

__global__ __launch_bounds__(512, 2) void k2_scan(
    unsigned short* __restrict__ GI,           // [51200][800] bf16 (deter -> cols 0..199)
    const unsigned short* __restrict__ Whh_p,
    const float* __restrict__ b_hh,
    float* __restrict__ out)                   // [51200][350] fp32 (cols 0..199 here)
{
    __shared__ unsigned short hS[16 * HSTRB];                 // 7424 B, bf16 h
    __shared__ float gAll[3 * 16 * GSTR];                     // 43584 B
    __shared__ __align__(16) unsigned short GIbuf[2][12288];  // 49152 B

    const int tid = threadIdx.x;
    const int w = tid >> 6, l = tid & 63;
    const int lo = l & 15, hi = l >> 4;
    const int r0 = blockIdx.x * 16;

    for (int i = tid; i < 16 * HSTRB; i += 512) hS[i] = 0;

    const int t0 = w * 5;
    const int ntl = (w == 7) ? 4 : 5;
    bf16x8 wf[5][7];
#pragma unroll
    for (int i = 0; i < 5; ++i)
#pragma unroll
        for (int kk = 0; kk < 7; ++kk)
            if (i < ntl)
                wf[i][kk] = __builtin_bit_cast(bf16x8,
                    *(const short8*)&Whh_p[((kk * 39 + (t0 + i)) * 64 + l) * 8]);

    int gOff[5];
#pragma unroll
    for (int i = 0; i < 5; ++i) {
        int nt = t0 + i; if (nt > 38) nt = 38;
        const int g = nt / 13, st = nt - g * 13;
        gOff[i] = (g * 16 + hi * 4) * GSTR + st * 16 + lo;
    }

    const char* srcB[3];
#pragma unroll
    for (int i = 0; i < 3; ++i) {
        int j = (i * 8 + w) * 64 + l;
        int rj = j / 75; int cj = j - rj * 75;
        if (rj > 15) { rj = 15; cj = 74; }
        srcB[i] = (const char*)GI + (size_t)(r0 + rj) * 50 * 1600 + (size_t)cj * 16;
    }

    const int c = tid & 255;
    const int rh = tid >> 8;
    const bool act = (c < 200);
    float bh0 = 0.f, bh1 = 0.f, bh2 = 0.f;
    if (act) { bh0 = b_hh[c]; bh1 = b_hh[200 + c]; bh2 = b_hh[400 + c]; }
    float h_reg[8] = {0.f, 0.f, 0.f, 0.f, 0.f, 0.f, 0.f, 0.f};

    {
#pragma unroll
        for (int i = 0; i < 3; ++i)
            gload_lds16(srcB[i], &GIbuf[0][(i * 8 + w) * 512]);
    }
    asm volatile("s_waitcnt lgkmcnt(0)" ::: "memory");
    __builtin_amdgcn_s_barrier();
    __builtin_amdgcn_sched_barrier(0);

    for (int t = 0; t < 50; ++t) {
        const int tn = (t < 49) ? t + 1 : 49;
        const int bsel = (t + 1) & 1;
#pragma unroll
        for (int i = 0; i < 3; ++i)
            gload_lds16(srcB[i] + (size_t)tn * 1600, &GIbuf[bsel][(i * 8 + w) * 512]);

        bf16x8 hf[7];
#pragma unroll
        for (int kk = 0; kk < 7; ++kk)
            hf[kk] = __builtin_bit_cast(bf16x8,
                *(const short8*)&hS[lo * HSTRB + kk * 32 + hi * 8]);
        f32x4 acc[5];
#pragma unroll
        for (int i = 0; i < 5; ++i) acc[i] = f32x4{0.f, 0.f, 0.f, 0.f};
#pragma unroll
        for (int i = 0; i < 5; ++i) if (i < ntl)
#pragma unroll
            for (int kk = 0; kk < 7; ++kk)
                acc[i] = __builtin_amdgcn_mfma_f32_16x16x32_bf16(hf[kk], wf[i][kk], acc[i], 0, 0, 0);

#pragma unroll
        for (int i = 0; i < 5; ++i) if (i < ntl)
#pragma unroll
            for (int r = 0; r < 4; ++r)
                gAll[gOff[i] + r * GSTR] = acc[i][r];

        asm volatile("s_waitcnt lgkmcnt(0)" ::: "memory");   // B1
        __builtin_amdgcn_s_barrier();
        __builtin_amdgcn_sched_barrier(0);
        asm volatile("s_waitcnt vmcnt(3)" ::: "memory");     // GIbuf[t&1] ready
        __builtin_amdgcn_sched_barrier(0);

        if (act) {
            const unsigned short* gib = &GIbuf[t & 1][0];
#pragma unroll
            for (int rr = 0; rr < 8; ++rr) {
                const int row = rh * 8 + rr;
                const float gi_r = bf2f(gib[row * 600 + c]);
                const float gi_z = bf2f(gib[row * 600 + 200 + c]);
                const float gi_n = bf2f(gib[row * 600 + 400 + c]);
                const float gr = gi_r + gAll[(0 * 16 + row) * GSTR + c] + bh0;
                const float gz = gi_z + gAll[(1 * 16 + row) * GSTR + c] + bh1;
                const float hn = gAll[(2 * 16 + row) * GSTR + c] + bh2;
                const float rs = __builtin_amdgcn_rcpf(1.f + __expf(-gr));
                const float zz = __builtin_amdgcn_rcpf(1.f + __expf(-gz));
                const float x  = gi_n + rs * hn;
                const float e2 = __expf(-2.f * fabsf(x));
                float th = (1.f - e2) * __builtin_amdgcn_rcpf(1.f + e2);
                th = __builtin_copysignf(th, x);
                const float h = (1.f - zz) * th + zz * h_reg[rr];
                h_reg[rr] = h;
                hS[row * HSTRB + c] = f2bf(h);
                const size_t bt = (size_t)((r0 + row) * 50 + t);
                out[bt * 350 + c] = h;                 // deter fp32
                GI[bt * 800 + c]  = f2bf(h);           // deter bf16 for k3
            }
        }

        asm volatile("s_waitcnt lgkmcnt(0)" ::: "memory");   // B2
        __builtin_amdgcn_s_barrier();
        __builtin_amdgcn_sched_barrier(0);
    }
}

// ---------------- kernel 3: heads, fully parallel over 51200 rows ----------------
__global__ __launch_bounds__(256, 1) void k3_heads(
    const unsigned short* __restrict__ GI,     // deter bf16 cols 0..199, QE cols 600..799
    const unsigned short* __restrict__ Wpq1,
    const unsigned short* __restrict__ Wpq2,
    const float* __restrict__ noise,           // [51200][30]
    const float* __restrict__ bp1,
    const float* __restrict__ bp2,
    const float* __restrict__ bq2,
    float* __restrict__ out)                   // cols 200..349
{
    __shared__ unsigned short pq[2][16 * HSTRB];
    __shared__ float ost[16 * 128];

    const int tid = threadIdx.x;
    const int w = tid >> 6, l = tid & 63;
    const int lo = l & 15, hi = l >> 4;
    const int r0 = blockIdx.x * 16;

    {   unsigned short* p0 = &pq[0][0];
        for (int i = tid; i < 2 * 16 * HSTRB; i += 256) p0[i] = 0; }
    __syncthreads();

    bf16x8 af[7];
#pragma unroll
    for (int kk = 0; kk < 7; ++kk)
        af[kk] = __builtin_bit_cast(bf16x8,
            *(const short8*)&GI[(size_t)(r0 + lo) * 800 + kk * 32 + hi * 8]);

    const int h1s = (w < 2) ? 7 * w : 14 + 6 * (w - 2);
    const int h1n = (w < 2) ? 7 : 6;
    f32x4 a2[7];
#pragma unroll
    for (int i = 0; i < 7; ++i) a2[i] = f32x4{0.f, 0.f, 0.f, 0.f};
#pragma unroll
    for (int i = 0; i < 7; ++i) if (i < h1n) {
        const int nt = h1s + i;
#pragma unroll
        for (int kk = 0; kk < 7; ++kk) {
            bf16x8 b = __builtin_bit_cast(bf16x8,
                *(const short8*)&Wpq1[((kk * 26 + nt) * 64 + l) * 8]);
            a2[i] = __builtin_amdgcn_mfma_f32_16x16x32_bf16(af[kk], b, a2[i], 0, 0, 0);
        }
    }
#pragma unroll
    for (int i = 0; i < 7; ++i) if (i < h1n) {
        const int nt = h1s + i;
        const bool isq = (nt >= 13);
        const int c1 = (isq ? (nt - 13) : nt) * 16 + lo;
        if (c1 < 200) {
#pragma unroll
            for (int r = 0; r < 4; ++r) {
                const int row = hi * 4 + r;
                float v = a2[i][r];
                if (isq) v += bf2f(GI[(size_t)(r0 + row) * 800 + 600 + c1]);  // QE (incl bq1)
                else     v += bp1[c1];
                v = (v > 0.f) ? v : expm1f(v);                                 // ELU
                pq[isq ? 1 : 0][row * HSTRB + c1] = f2bf(v);
            }
        }
    }
    __syncthreads();

    const unsigned short* srcS = &pq[(w >= 2) ? 1 : 0][0];
    bf16x8 pf[7];
#pragma unroll
    for (int kk = 0; kk < 7; ++kk)
        pf[kk] = __builtin_bit_cast(bf16x8,
            *(const short8*)&srcS[lo * HSTRB + kk * 32 + hi * 8]);
    f32x4 a3[2];
    a3[0] = f32x4{0.f, 0.f, 0.f, 0.f};
    a3[1] = f32x4{0.f, 0.f, 0.f, 0.f};
#pragma unroll
    for (int i = 0; i < 2; ++i) {
        const int nt = ((w >= 2) ? 4 : 0) + (w & 1) * 2 + i;
#pragma unroll
        for (int kk = 0; kk < 7; ++kk) {
            bf16x8 b = __builtin_bit_cast(bf16x8,
                *(const short8*)&Wpq2[((kk * 8 + nt) * 64 + l) * 8]);
            a3[i] = __builtin_amdgcn_mfma_f32_16x16x32_bf16(pf[kk], b, a3[i], 0, 0, 0);
        }
    }
#pragma unroll
    for (int i = 0; i < 2; ++i) {
        const int nt = ((w >= 2) ? 4 : 0) + (w & 1) * 2 + i;
        const int cl = (nt & 3) * 16 + lo;
        if (cl < 60) {
            const float bb = (nt < 4) ? bp2[cl] : bq2[cl];
            const int obase = ((nt < 4) ? 0 : 64) + ((cl < 30) ? cl : (32 + cl - 30));
#pragma unroll
            for (int r = 0; r < 4; ++r)
                ost[(hi * 4 + r) * 128 + obase] = a3[i][r] + bb;
        }
    }
    __syncthreads();

    for (int idx = tid; idx < 16 * 150; idx += 256) {
        const int row = idx / 150;
        const int c = 200 + (idx - row * 150);
        const size_t bt = (size_t)(r0 + row);
        const float* o = &ost[row * 128];
        float v;
        if (c < 230) {
            const int j = c - 200;
            const float qs = softplusf(o[96 + j]) + 0.1f;
            v = o[64 + j] + qs * noise[bt * 30 + j];
        }
        else if (c < 260) v = o[c - 230];
        else if (c < 290) v = softplusf(o[32 + (c - 260)]) + 0.1f;
        else if (c < 320) v = o[64 + (c - 290)];
        else              v = softplusf(o[96 + (c - 320)]) + 0.1f;
        out[bt * 350 + c] = v;
    }
}

// ---------------------------------------------------------------------------
extern "C" void kernel_launch(void* const* d_in, const int* in_sizes, int n_in,
                              void* d_out, int out_size, void* d_ws, size_t ws_size,
                              hipStream_t stream)
{
    const float* action = (const float*)d_in[0];
    const float* embed  = (const float*)d_in[1];
    const float* noise  = (const float*)d_in[2];
    const float* W_ih   = (const float*)d_in[3];
    const float* W_hh   = (const float*)d_in[4];
    const float* b_ih   = (const float*)d_in[5];
    const float* b_hh   = (const float*)d_in[6];
    const float* Wp1    = (const float*)d_in[7];
    const float* bp1    = (const float*)d_in[8];
    const float* Wp2    = (const float*)d_in[9];
    const float* bp2    = (const float*)d_in[10];
    const float* Wq1    = (const float*)d_in[11];
    const float* bq1    = (const float*)d_in[12];
    const float* Wq2    = (const float*)d_in[13];
    const float* bq2    = (const float*)d_in[14];
    (void)in_sizes; (void)n_in; (void)out_size; (void)ws_size;

    char* ws = (char*)d_ws;
    unsigned short* GI    = (unsigned short*)(ws);
    unsigned short* Bpack = (unsigned short*)(ws + OFF_BPACK);
    unsigned short* Whh_p = (unsigned short*)(ws + OFF_WHH);
    unsigned short* Wpq1  = (unsigned short*)(ws + OFF_WPQ1);
    unsigned short* Wpq2  = (unsigned short*)(ws + OFF_WPQ2);
    float* outp = (float*)d_out;

    pack_kernel<<<4222, 256, 0, stream>>>(W_ih, W_hh, Wp1, Wq1, Wp2, Wq2,
                                          Bpack, Whh_p, Wpq1, Wpq2);
    k1_gi<<<2000, 256, 0, stream>>>(embed, action, W_ih, b_ih, bq1, Bpack, GI);
    k2_scan<<<64, 512, 0, stream>>>(GI, Whh_p, b_hh, outp);
    k3_heads<<<3200, 256, 0, stream>>>(GI, Wpq1, Wpq2, noise, bp1, bp2, bq2, outp);
}

// Round 9
// 369.769 us; speedup vs baseline: 2.2362x; 1.1345x over previous
//
#include <hip/hip_runtime.h>
#include <hip/hip_bf16.h>
#include <cstdint>

// ---------------------------------------------------------------------------
// WorldModel RSSM: B=1024 T=50 E=1024 A=6 S=200 H=200 L=30
// fp32 in/out; internal GEMMs bf16 MFMA w/ fp32 accum.
//
//   k1: GI[bt,0:600]=concat(a,e)@W_ih+b_ih ; GI[bt,600:800]=e@Wq1[200:]+bq1
//       counted-vmcnt 2-deep pipeline (T3/T4: wait targets loads issued one
//       FULL iteration ago, never drain to 0 in-loop); A staged row-major
//       fp32 via dense 8-row x 128B global_load_lds (bank-balanced reads).
//   k2: GRU scan, 64 blocks x 8 waves, W_hh resident in regs (round 7).
//   k3: heads (fc_prior/fc_posterior + softplus + rsample) fully parallel.
// ---------------------------------------------------------------------------

typedef __attribute__((ext_vector_type(8))) short   short8;
typedef __attribute__((ext_vector_type(8))) __bf16  bf16x8;
typedef __attribute__((ext_vector_type(4))) float   f32x4;

__device__ __forceinline__ float bf2f(unsigned short u) {
    unsigned int v = ((unsigned int)u) << 16;
    return __builtin_bit_cast(float, v);
}
__device__ __forceinline__ unsigned short f2bf(float f) {
    unsigned int v = __builtin_bit_cast(unsigned int, f);
    v = v + 0x7FFFu + ((v >> 16) & 1u);   // RNE
    return (unsigned short)(v >> 16);
}
__device__ __forceinline__ float softplusf(float x) {
    return (x > 20.f) ? x : log1pf(__expf(x));
}
__device__ __forceinline__ void gload_lds16(const void* g, void* l) {
    __builtin_amdgcn_global_load_lds(
        (const __attribute__((address_space(1))) void*)g,
        (__attribute__((address_space(3))) void*)l, 16, 0, 0);
}

// ---------------- workspace layout (bytes) ----------------
#define OFF_BPACK 81920000
#define OFF_WHH   83558400
#define OFF_WPQ1  83837952
#define OFF_WPQ2  84024320

// fragment mapping (mfma_f32_16x16x32_bf16):
//   A[l&15][(l>>4)*8+j], B[(l>>4)*8+j][l&15], D[(l>>4)*4+r][l&15]
// packed B storage: elem = ((kk*NT + nt)*64 + l)*8 + j

__global__ __launch_bounds__(256) void pack_kernel(
    const float* __restrict__ W_ih, const float* __restrict__ W_hh,
    const float* __restrict__ Wp1,  const float* __restrict__ Wq1,
    const float* __restrict__ Wp2,  const float* __restrict__ Wq2,
    unsigned short* __restrict__ Bpack, unsigned short* __restrict__ Whh_p,
    unsigned short* __restrict__ Wpq1,  unsigned short* __restrict__ Wpq2)
{
    int e = blockIdx.x * 256 + threadIdx.x;
    if (e < 819200) {                       // k1: K=1024(embed), N=800
        const int j = e & 7, l = (e >> 3) & 63;
        const int nt = (e >> 9) % 50, kk = e / (512 * 50);
        const int k = kk * 32 + (l >> 4) * 8 + j;
        const int c = nt * 16 + (l & 15);
        Bpack[e] = f2bf((c < 600) ? W_ih[(6 + k) * 600 + c]
                                  : Wq1[(200 + k) * 200 + (c - 600)]);
        return;
    }
    e -= 819200;
    if (e < 139776) {                       // W_hh: K pad 224, N = 3 gates x 13 tiles
        const int j = e & 7, l = (e >> 3) & 63;
        const int nt = (e >> 9) % 39, kk = e / (512 * 39);
        const int k = kk * 32 + (l >> 4) * 8 + j;
        const int g = nt / 13, st = nt % 13;
        const int c = st * 16 + (l & 15);
        Whh_p[e] = (k < 200 && c < 200) ? f2bf(W_hh[k * 600 + g * 200 + c]) : (unsigned short)0;
        return;
    }
    e -= 139776;
    if (e < 93184) {                        // heads1: [Wp1 | Wq1[:200]] K pad 224
        const int j = e & 7, l = (e >> 3) & 63;
        const int nt = (e >> 9) % 26, kk = e / (512 * 26);
        const int k = kk * 32 + (l >> 4) * 8 + j;
        unsigned short v = 0;
        if (nt < 13) { const int c = nt * 16 + (l & 15);        if (k < 200 && c < 200) v = f2bf(Wp1[k * 200 + c]); }
        else         { const int c = (nt - 13) * 16 + (l & 15); if (k < 200 && c < 200) v = f2bf(Wq1[k * 200 + c]); }
        Wpq1[e] = v;
        return;
    }
    e -= 93184;
    if (e < 28672) {                        // heads2: [Wp2 | Wq2] N pad 64 each
        const int j = e & 7, l = (e >> 3) & 63;
        const int nt = (e >> 9) % 8, kk = e / (512 * 8);
        const int k = kk * 32 + (l >> 4) * 8 + j;
        unsigned short v = 0;
        if (nt < 4) { const int c = nt * 16 + (l & 15);       if (k < 200 && c < 60) v = f2bf(Wp2[k * 60 + c]); }
        else        { const int c = (nt - 4) * 16 + (l & 15); if (k < 200 && c < 60) v = f2bf(Wq2[k * 60 + c]); }
        Wpq2[e] = v;
    }
}

// ---------------- kernel 1: GI/QE GEMM  M=51200 N=800 K=1024 ----------------
// grid 2000 = 400 M-chunks(128 rows) x 5 N-groups(160 cols = 10 tiles).
// 256 thr = 4 waves; wave w -> M-subtiles {2w,2w+1} x all 10 N-tiles.
// Buffer layout (bytes): [0,10240) B 10 tiles; [10240,26624) A 128 rows x 128B
// (row-major fp32). 26 stage chunks/K-step (10 B + 16 A), all dense lines.
// Pipeline: issue(kk+1) -> vmcnt(Lw) [= kk's loads done] -> bar -> compute ->
// lgkm(0)+bar. vmcnt never drains to 0 in-loop.
#define K1_BYTES 26624
__global__ __launch_bounds__(256, 3) void k1_gi(
    const float* __restrict__ embed,   // [51200][1024]
    const float* __restrict__ action,  // [51200][6]
    const float* __restrict__ W_ih,    // rows 0..5 = action part
    const float* __restrict__ b_ih,
    const float* __restrict__ bq1,
    const unsigned short* __restrict__ Bpack,
    unsigned short* __restrict__ GI)   // [51200][800] bf16
{
    __shared__ char bufS[2][K1_BYTES];

    const int tid = threadIdx.x;
    const int w = tid >> 6, l = tid & 63;
    const int lo = l & 15, hi = l >> 4;

    // XCD-bijective swizzle: 5 N-siblings of an M-chunk land on one XCD
    const int g    = (blockIdx.x & 7) * 250 + (blockIdx.x >> 3);
    const int mblk = g / 5;
    const int ng   = g - mblk * 5;
    const int rb   = mblk * 128;

    // ---- stage-chunk setup: 26 chunks, wave w does j = w + 4i  (w<2: 7, else 6)
    const char* sp[7]; int st[7]; int dof[7];
    const int nch = (w < 2) ? 7 : 6;
#pragma unroll
    for (int i = 0; i < 7; ++i) {
        int j = w + 4 * i; if (j >= 26) j = 25;
        if (j < 10) {                      // B tile j: 1KB linear from Bpack
            sp[i]  = (const char*)Bpack + (size_t)(ng * 10 + j) * 1024 + l * 16;
            st[i]  = 50 * 1024;            // bytes per kk
            dof[i] = j * 1024;
        } else {                           // A chunk: 8 rows x 128B dense
            const int a = j - 10;
            sp[i]  = (const char*)embed
                   + (size_t)(rb + a * 8 + (l >> 3)) * 4096 + (l & 7) * 16;
            st[i]  = 128;                  // bytes per kk
            dof[i] = 10240 + a * 1024;
        }
    }

    f32x4 acc[2][10];
#pragma unroll
    for (int m = 0; m < 2; ++m)
#pragma unroll
        for (int i = 0; i < 10; ++i) acc[m][i] = f32x4{0.f, 0.f, 0.f, 0.f};

    // ---- prologue: issue stage kk=0 -> buf0 (no wait here)
#pragma unroll
    for (int i = 0; i < 7; ++i) if (i < nch) {
        gload_lds16(sp[i], &bufS[0][dof[i]]);
        sp[i] += st[i];
    }

    // ---- main loop
    int cur = 0;
    for (int kk = 0; kk < 32; ++kk) {
        const int nxt = cur ^ 1;
        if (kk < 31) {
            // issue stage(kk+1); safe: all waves finished reading buf nxt at
            // the end-barrier of iteration kk-1.
#pragma unroll
            for (int i = 0; i < 7; ++i) if (i < nch) {
                gload_lds16(sp[i], &bufS[nxt][dof[i]]);
                sp[i] += st[i];
            }
            if (w < 2) asm volatile("s_waitcnt vmcnt(7)" ::: "memory");
            else       asm volatile("s_waitcnt vmcnt(6)" ::: "memory");
        } else {
            asm volatile("s_waitcnt vmcnt(0)" ::: "memory");
        }
        __builtin_amdgcn_s_barrier();          // buf cur fully staged, all waves
        __builtin_amdgcn_sched_barrier(0);

        // A fragments: row-major fp32 read (bank-balanced) + convert
        const float* Af = (const float*)&bufS[cur][10240];
        bf16x8 af[2];
#pragma unroll
        for (int m = 0; m < 2; ++m) {
            const int ms = w * 2 + m;
            const float* rp = Af + (ms * 16 + lo) * 32 + hi * 8;
            f32x4 v0 = *(const f32x4*)rp;
            f32x4 v1 = *(const f32x4*)(rp + 4);
            bf16x8 t;
#pragma unroll
            for (int q = 0; q < 4; ++q) { t[q] = (__bf16)v0[q]; t[4 + q] = (__bf16)v1[q]; }
            af[m] = t;
        }
#pragma unroll
        for (int i = 0; i < 10; ++i) {
            bf16x8 b = __builtin_bit_cast(bf16x8,
                *(const short8*)&bufS[cur][i * 1024 + l * 16]);
            acc[0][i] = __builtin_amdgcn_mfma_f32_16x16x32_bf16(af[0], b, acc[0][i], 0, 0, 0);
            acc[1][i] = __builtin_amdgcn_mfma_f32_16x16x32_bf16(af[1], b, acc[1][i], 0, 0, 0);
        }

        asm volatile("s_waitcnt lgkmcnt(0)" ::: "memory");   // all LDS reads done
        __builtin_amdgcn_s_barrier();          // buf cur may be overwritten next
        __builtin_amdgcn_sched_barrier(0);
        cur = nxt;
    }

    // ---- epilogue: bias + action(K=6) contribution, store bf16
#pragma unroll
    for (int m = 0; m < 2; ++m) {
        const int rbase = rb + (w * 2 + m) * 16 + hi * 4;
        float av[4][6];
#pragma unroll
        for (int r = 0; r < 4; ++r)
#pragma unroll
            for (int k = 0; k < 6; ++k) av[r][k] = action[(size_t)(rbase + r) * 6 + k];
#pragma unroll
        for (int i = 0; i < 10; ++i) {
            const int col = ng * 160 + i * 16 + lo;
            const float bias = (col < 600) ? b_ih[col] : bq1[col - 600];
            float wa[6];
            if (col < 600) {
#pragma unroll
                for (int k = 0; k < 6; ++k) wa[k] = W_ih[k * 600 + col];
            }
#pragma unroll
            for (int r = 0; r < 4; ++r) {
                float v = acc[m][i][r] + bias;
                if (col < 600) {
#pragma unroll
                    for (int k = 0; k < 6; ++k) v += av[r][k] * wa[k];
                }
                GI[(size_t)(rbase + r) * 800 + col] = f2bf(v);
            }
        }
    }
}

// ---------------- kernel 2: GRU scan, 8 waves, resident weights ----------------
#define HSTRB 232   // hS row stride in bf16 elems (K pad >=224)
#define GSTR  227   // gAll row stride in floats (odd-ish vs 32 banks)

__global__ __launch_bounds__(512, 2) void k2_scan(
    unsigned short* __restrict__ GI,           // [51200][800] bf16 (deter -> cols 0..199)
    const unsigned short* __restrict__ Whh_p,
    const float* __restrict__ b_hh,
    float* __restrict__ out)                   // [51200][350] fp32 (cols 0..199 here)
{
    __shared__ unsigned short hS[16 * HSTRB];                 // 7424 B, bf16 h
    __shared__ float gAll[3 * 16 * GSTR];                     // 43584 B
    __shared__ __align__(16) unsigned short GIbuf[2][12288];  // 49152 B

    const int tid = threadIdx.x;
    const int w = tid >> 6, l = tid & 63;
    const int lo = l & 15, hi = l >> 4;
    const int r0 = blockIdx.x * 16;

    for (int i = tid; i < 16 * HSTRB; i += 512) hS[i] = 0;

    const int t0 = w * 5;
    const int ntl = (w == 7) ? 4 : 5;
    bf16x8 wf[5][7];
#pragma unroll
    for (int i = 0; i < 5; ++i)
#pragma unroll
        for (int kk = 0; kk < 7; ++kk)
            if (i < ntl)
                wf[i][kk] = __builtin_bit_cast(bf16x8,
                    *(const short8*)&Whh_p[((kk * 39 + (t0 + i)) * 64 + l) * 8]);

    int gOff[5];
#pragma unroll
    for (int i = 0; i < 5; ++i) {
        int nt = t0 + i; if (nt > 38) nt = 38;
        const int g = nt / 13, st = nt - g * 13;
        gOff[i] = (g * 16 + hi * 4) * GSTR + st * 16 + lo;
    }

    const char* srcB[3];
#pragma unroll
    for (int i = 0; i < 3; ++i) {
        int j = (i * 8 + w) * 64 + l;
        int rj = j / 75; int cj = j - rj * 75;
        if (rj > 15) { rj = 15; cj = 74; }
        srcB[i] = (const char*)GI + (size_t)(r0 + rj) * 50 * 1600 + (size_t)cj * 16;
    }

    const int c = tid & 255;
    const int rh = tid >> 8;
    const bool act = (c < 200);
    float bh0 = 0.f, bh1 = 0.f, bh2 = 0.f;
    if (act) { bh0 = b_hh[c]; bh1 = b_hh[200 + c]; bh2 = b_hh[400 + c]; }
    float h_reg[8] = {0.f, 0.f, 0.f, 0.f, 0.f, 0.f, 0.f, 0.f};

    {
#pragma unroll
        for (int i = 0; i < 3; ++i)
            gload_lds16(srcB[i], &GIbuf[0][(i * 8 + w) * 512]);
    }
    asm volatile("s_waitcnt lgkmcnt(0)" ::: "memory");
    __builtin_amdgcn_s_barrier();
    __builtin_amdgcn_sched_barrier(0);

    for (int t = 0; t < 50; ++t) {
        const int tn = (t < 49) ? t + 1 : 49;
        const int bsel = (t + 1) & 1;
#pragma unroll
        for (int i = 0; i < 3; ++i)
            gload_lds16(srcB[i] + (size_t)tn * 1600, &GIbuf[bsel][(i * 8 + w) * 512]);

        bf16x8 hf[7];
#pragma unroll
        for (int kk = 0; kk < 7; ++kk)
            hf[kk] = __builtin_bit_cast(bf16x8,
                *(const short8*)&hS[lo * HSTRB + kk * 32 + hi * 8]);
        f32x4 acc[5];
#pragma unroll
        for (int i = 0; i < 5; ++i) acc[i] = f32x4{0.f, 0.f, 0.f, 0.f};
#pragma unroll
        for (int i = 0; i < 5; ++i) if (i < ntl)
#pragma unroll
            for (int kk = 0; kk < 7; ++kk)
                acc[i] = __builtin_amdgcn_mfma_f32_16x16x32_bf16(hf[kk], wf[i][kk], acc[i], 0, 0, 0);

#pragma unroll
        for (int i = 0; i < 5; ++i) if (i < ntl)
#pragma unroll
            for (int r = 0; r < 4; ++r)
                gAll[gOff[i] + r * GSTR] = acc[i][r];

        asm volatile("s_waitcnt lgkmcnt(0)" ::: "memory");   // B1
        __builtin_amdgcn_s_barrier();
        __builtin_amdgcn_sched_barrier(0);
        asm volatile("s_waitcnt vmcnt(3)" ::: "memory");     // GIbuf[t&1] ready
        __builtin_amdgcn_sched_barrier(0);

        if (act) {
            const unsigned short* gib = &GIbuf[t & 1][0];
#pragma unroll
            for (int rr = 0; rr < 8; ++rr) {
                const int row = rh * 8 + rr;
                const float gi_r = bf2f(gib[row * 600 + c]);
                const float gi_z = bf2f(gib[row * 600 + 200 + c]);
                const float gi_n = bf2f(gib[row * 600 + 400 + c]);
                const float gr = gi_r + gAll[(0 * 16 + row) * GSTR + c] + bh0;
                const float gz = gi_z + gAll[(1 * 16 + row) * GSTR + c] + bh1;
                const float hn = gAll[(2 * 16 + row) * GSTR + c] + bh2;
                const float rs = __builtin_amdgcn_rcpf(1.f + __expf(-gr));
                const float zz = __builtin_amdgcn_rcpf(1.f + __expf(-gz));
                const float x  = gi_n + rs * hn;
                const float e2 = __expf(-2.f * fabsf(x));
                float th = (1.f - e2) * __builtin_amdgcn_rcpf(1.f + e2);
                th = __builtin_copysignf(th, x);
                const float h = (1.f - zz) * th + zz * h_reg[rr];
                h_reg[rr] = h;
                hS[row * HSTRB + c] = f2bf(h);
                const size_t bt = (size_t)((r0 + row) * 50 + t);
                out[bt * 350 + c] = h;                 // deter fp32
                GI[bt * 800 + c]  = f2bf(h);           // deter bf16 for k3
            }
        }

        asm volatile("s_waitcnt lgkmcnt(0)" ::: "memory");   // B2
        __builtin_amdgcn_s_barrier();
        __builtin_amdgcn_sched_barrier(0);
    }
}

// ---------------- kernel 3: heads, fully parallel over 51200 rows ----------------
__global__ __launch_bounds__(256, 1) void k3_heads(
    const unsigned short* __restrict__ GI,     // deter bf16 cols 0..199, QE cols 600..799
    const unsigned short* __restrict__ Wpq1,
    const unsigned short* __restrict__ Wpq2,
    const float* __restrict__ noise,           // [51200][30]
    const float* __restrict__ bp1,
    const float* __restrict__ bp2,
    const float* __restrict__ bq2,
    float* __restrict__ out)                   // cols 200..349
{
    __shared__ unsigned short pq[2][16 * HSTRB];
    __shared__ float ost[16 * 128];

    const int tid = threadIdx.x;
    const int w = tid >> 6, l = tid & 63;
    const int lo = l & 15, hi = l >> 4;
    const int r0 = blockIdx.x * 16;

    {   unsigned short* p0 = &pq[0][0];
        for (int i = tid; i < 2 * 16 * HSTRB; i += 256) p0[i] = 0; }
    __syncthreads();

    bf16x8 af[7];
#pragma unroll
    for (int kk = 0; kk < 7; ++kk)
        af[kk] = __builtin_bit_cast(bf16x8,
            *(const short8*)&GI[(size_t)(r0 + lo) * 800 + kk * 32 + hi * 8]);

    const int h1s = (w < 2) ? 7 * w : 14 + 6 * (w - 2);
    const int h1n = (w < 2) ? 7 : 6;
    f32x4 a2[7];
#pragma unroll
    for (int i = 0; i < 7; ++i) a2[i] = f32x4{0.f, 0.f, 0.f, 0.f};
#pragma unroll
    for (int i = 0; i < 7; ++i) if (i < h1n) {
        const int nt = h1s + i;
#pragma unroll
        for (int kk = 0; kk < 7; ++kk) {
            bf16x8 b = __builtin_bit_cast(bf16x8,
                *(const short8*)&Wpq1[((kk * 26 + nt) * 64 + l) * 8]);
            a2[i] = __builtin_amdgcn_mfma_f32_16x16x32_bf16(af[kk], b, a2[i], 0, 0, 0);
        }
    }
#pragma unroll
    for (int i = 0; i < 7; ++i) if (i < h1n) {
        const int nt = h1s + i;
        const bool isq = (nt >= 13);
        const int c1 = (isq ? (nt - 13) : nt) * 16 + lo;
        if (c1 < 200) {
#pragma unroll
            for (int r = 0; r < 4; ++r) {
                const int row = hi * 4 + r;
                float v = a2[i][r];
                if (isq) v += bf2f(GI[(size_t)(r0 + row) * 800 + 600 + c1]);  // QE (incl bq1)
                else     v += bp1[c1];
                v = (v > 0.f) ? v : expm1f(v);                                 // ELU
                pq[isq ? 1 : 0][row * HSTRB + c1] = f2bf(v);
            }
        }
    }
    __syncthreads();

    const unsigned short* srcS = &pq[(w >= 2) ? 1 : 0][0];
    bf16x8 pf[7];
#pragma unroll
    for (int kk = 0; kk < 7; ++kk)
        pf[kk] = __builtin_bit_cast(bf16x8,
            *(const short8*)&srcS[lo * HSTRB + kk * 32 + hi * 8]);
    f32x4 a3[2];
    a3[0] = f32x4{0.f, 0.f, 0.f, 0.f};
    a3[1] = f32x4{0.f, 0.f, 0.f, 0.f};
#pragma unroll
    for (int i = 0; i < 2; ++i) {
        const int nt = ((w >= 2) ? 4 : 0) + (w & 1) * 2 + i;
#pragma unroll
        for (int kk = 0; kk < 7; ++kk) {
            bf16x8 b = __builtin_bit_cast(bf16x8,
                *(const short8*)&Wpq2[((kk * 8 + nt) * 64 + l) * 8]);
            a3[i] = __builtin_amdgcn_mfma_f32_16x16x32_bf16(pf[kk], b, a3[i], 0, 0, 0);
        }
    }
#pragma unroll
    for (int i = 0; i < 2; ++i) {
        const int nt = ((w >= 2) ? 4 : 0) + (w & 1) * 2 + i;
        const int cl = (nt & 3) * 16 + lo;
        if (cl < 60) {
            const float bb = (nt < 4) ? bp2[cl] : bq2[cl];
            const int obase = ((nt < 4) ? 0 : 64) + ((cl < 30) ? cl : (32 + cl - 30));
#pragma unroll
            for (int r = 0; r < 4; ++r)
                ost[(hi * 4 + r) * 128 + obase] = a3[i][r] + bb;
        }
    }
    __syncthreads();

    for (int idx = tid; idx < 16 * 150; idx += 256) {
        const int row = idx / 150;
        const int c = 200 + (idx - row * 150);
        const size_t bt = (size_t)(r0 + row);
        const float* o = &ost[row * 128];
        float v;
        if (c < 230) {
            const int j = c - 200;
            const float qs = softplusf(o[96 + j]) + 0.1f;
            v = o[64 + j] + qs * noise[bt * 30 + j];
        }
        else if (c < 260) v = o[c - 230];
        else if (c < 290) v = softplusf(o[32 + (c - 260)]) + 0.1f;
        else if (c < 320) v = o[64 + (c - 290)];
        else              v = softplusf(o[96 + (c - 320)]) + 0.1f;
        out[bt * 350 + c] = v;
    }
}

// ---------------------------------------------------------------------------
extern "C" void kernel_launch(void* const* d_in, const int* in_sizes, int n_in,
                              void* d_out, int out_size, void* d_ws, size_t ws_size,
                              hipStream_t stream)
{
    const float* action = (const float*)d_in[0];
    const float* embed  = (const float*)d_in[1];
    const float* noise  = (const float*)d_in[2];
    const float* W_ih   = (const float*)d_in[3];
    const float* W_hh   = (const float*)d_in[4];
    const float* b_ih   = (const float*)d_in[5];
    const float* b_hh   = (const float*)d_in[6];
    const float* Wp1    = (const float*)d_in[7];
    const float* bp1    = (const float*)d_in[8];
    const float* Wp2    = (const float*)d_in[9];
    const float* bp2    = (const float*)d_in[10];
    const float* Wq1    = (const float*)d_in[11];
    const float* bq1    = (const float*)d_in[12];
    const float* Wq2    = (const float*)d_in[13];
    const float* bq2    = (const float*)d_in[14];
    (void)in_sizes; (void)n_in; (void)out_size; (void)ws_size;

    char* ws = (char*)d_ws;
    unsigned short* GI    = (unsigned short*)(ws);
    unsigned short* Bpack = (unsigned short*)(ws + OFF_BPACK);
    unsigned short* Whh_p = (unsigned short*)(ws + OFF_WHH);
    unsigned short* Wpq1  = (unsigned short*)(ws + OFF_WPQ1);
    unsigned short* Wpq2  = (unsigned short*)(ws + OFF_WPQ2);
    float* outp = (float*)d_out;

    pack_kernel<<<4222, 256, 0, stream>>>(W_ih, W_hh, Wp1, Wq1, Wp2, Wq2,
                                          Bpack, Whh_p, Wpq1, Wpq2);
    k1_gi<<<2000, 256, 0, stream>>>(embed, action, W_ih, b_ih, bq1, Bpack, GI);
    k2_scan<<<64, 512, 0, stream>>>(GI, Whh_p, b_hh, outp);
    k3_heads<<<3200, 256, 0, stream>>>(GI, Wpq1, Wpq2, noise, bp1, bp2, bq2, outp);
}

// Round 10
// 367.893 us; speedup vs baseline: 2.2476x; 1.0051x over previous
//
#include <hip/hip_runtime.h>
#include <hip/hip_bf16.h>
#include <cstdint>

// ---------------------------------------------------------------------------
// WorldModel RSSM: B=1024 T=50 E=1024 A=6 S=200 H=200 L=30
// fp32 in/out; internal GEMMs bf16 MFMA w/ fp32 accum.
//
//   k1: GI[bt,0:600]=concat(a,e)@W_ih+b_ih ; GI[bt,600:800]=e@Wq1[200:]+bq1
//       counted-vmcnt 2-deep pipeline; A staged row-major fp32 with XOR
//       bank-swizzle (source-permuted global_load_lds + swizzled read:
//       rule 21 both-sides involution) -> 16-way conflict eliminated.
//   k2: GRU scan, 64 blocks x 8 waves, W_hh resident in regs (round 7).
//   k3: heads (fc_prior/fc_posterior + softplus + rsample) fully parallel.
// ---------------------------------------------------------------------------

typedef __attribute__((ext_vector_type(8))) short   short8;
typedef __attribute__((ext_vector_type(8))) __bf16  bf16x8;
typedef __attribute__((ext_vector_type(4))) float   f32x4;

__device__ __forceinline__ float bf2f(unsigned short u) {
    unsigned int v = ((unsigned int)u) << 16;
    return __builtin_bit_cast(float, v);
}
__device__ __forceinline__ unsigned short f2bf(float f) {
    unsigned int v = __builtin_bit_cast(unsigned int, f);
    v = v + 0x7FFFu + ((v >> 16) & 1u);   // RNE
    return (unsigned short)(v >> 16);
}
__device__ __forceinline__ float softplusf(float x) {
    return (x > 20.f) ? x : log1pf(__expf(x));
}
__device__ __forceinline__ void gload_lds16(const void* g, void* l) {
    __builtin_amdgcn_global_load_lds(
        (const __attribute__((address_space(1))) void*)g,
        (__attribute__((address_space(3))) void*)l, 16, 0, 0);
}

// ---------------- workspace layout (bytes) ----------------
#define OFF_BPACK 81920000
#define OFF_WHH   83558400
#define OFF_WPQ1  83837952
#define OFF_WPQ2  84024320

// fragment mapping (mfma_f32_16x16x32_bf16):
//   A[l&15][(l>>4)*8+j], B[(l>>4)*8+j][l&15], D[(l>>4)*4+r][l&15]
// packed B storage: elem = ((kk*NT + nt)*64 + l)*8 + j

__global__ __launch_bounds__(256) void pack_kernel(
    const float* __restrict__ W_ih, const float* __restrict__ W_hh,
    const float* __restrict__ Wp1,  const float* __restrict__ Wq1,
    const float* __restrict__ Wp2,  const float* __restrict__ Wq2,
    unsigned short* __restrict__ Bpack, unsigned short* __restrict__ Whh_p,
    unsigned short* __restrict__ Wpq1,  unsigned short* __restrict__ Wpq2)
{
    int e = blockIdx.x * 256 + threadIdx.x;
    if (e < 819200) {                       // k1: K=1024(embed), N=800
        const int j = e & 7, l = (e >> 3) & 63;
        const int nt = (e >> 9) % 50, kk = e / (512 * 50);
        const int k = kk * 32 + (l >> 4) * 8 + j;
        const int c = nt * 16 + (l & 15);
        Bpack[e] = f2bf((c < 600) ? W_ih[(6 + k) * 600 + c]
                                  : Wq1[(200 + k) * 200 + (c - 600)]);
        return;
    }
    e -= 819200;
    if (e < 139776) {                       // W_hh: K pad 224, N = 3 gates x 13 tiles
        const int j = e & 7, l = (e >> 3) & 63;
        const int nt = (e >> 9) % 39, kk = e / (512 * 39);
        const int k = kk * 32 + (l >> 4) * 8 + j;
        const int g = nt / 13, st = nt % 13;
        const int c = st * 16 + (l & 15);
        Whh_p[e] = (k < 200 && c < 200) ? f2bf(W_hh[k * 600 + g * 200 + c]) : (unsigned short)0;
        return;
    }
    e -= 139776;
    if (e < 93184) {                        // heads1: [Wp1 | Wq1[:200]] K pad 224
        const int j = e & 7, l = (e >> 3) & 63;
        const int nt = (e >> 9) % 26, kk = e / (512 * 26);
        const int k = kk * 32 + (l >> 4) * 8 + j;
        unsigned short v = 0;
        if (nt < 13) { const int c = nt * 16 + (l & 15);        if (k < 200 && c < 200) v = f2bf(Wp1[k * 200 + c]); }
        else         { const int c = (nt - 13) * 16 + (l & 15); if (k < 200 && c < 200) v = f2bf(Wq1[k * 200 + c]); }
        Wpq1[e] = v;
        return;
    }
    e -= 93184;
    if (e < 28672) {                        // heads2: [Wp2 | Wq2] N pad 64 each
        const int j = e & 7, l = (e >> 3) & 63;
        const int nt = (e >> 9) % 8, kk = e / (512 * 8);
        const int k = kk * 32 + (l >> 4) * 8 + j;
        unsigned short v = 0;
        if (nt < 4) { const int c = nt * 16 + (l & 15);       if (k < 200 && c < 60) v = f2bf(Wp2[k * 60 + c]); }
        else        { const int c = (nt - 4) * 16 + (l & 15); if (k < 200 && c < 60) v = f2bf(Wq2[k * 60 + c]); }
        Wpq2[e] = v;
    }
}

// ---------------- kernel 1: GI/QE GEMM  M=51200 N=800 K=1024 ----------------
// grid 2000 = 400 M-chunks(128 rows) x 5 N-groups(160 cols = 10 tiles).
// 256 thr = 4 waves; wave w -> M-subtiles {2w,2w+1} x all 10 N-tiles.
// Buffer (bytes): [0,10240) B 10 tiles; [10240,26624) A 128 rows x 128B fp32,
// A region XOR-swizzled: LDS quad u of row r holds global quad u^(r&7).
// Staging source permuted to match (global_load_lds dest stays linear).
// Pipeline: issue(kk+1) -> vmcnt(Lw) -> bar -> compute -> lgkm(0) -> bar.
#define K1_BYTES 26624
__global__ __launch_bounds__(256, 3) void k1_gi(
    const float* __restrict__ embed,   // [51200][1024]
    const float* __restrict__ action,  // [51200][6]
    const float* __restrict__ W_ih,    // rows 0..5 = action part
    const float* __restrict__ b_ih,
    const float* __restrict__ bq1,
    const unsigned short* __restrict__ Bpack,
    unsigned short* __restrict__ GI)   // [51200][800] bf16
{
    __shared__ char bufS[2][K1_BYTES];

    const int tid = threadIdx.x;
    const int w = tid >> 6, l = tid & 63;
    const int lo = l & 15, hi = l >> 4;

    // XCD-bijective swizzle: 5 N-siblings of an M-chunk land on one XCD
    const int g    = (blockIdx.x & 7) * 250 + (blockIdx.x >> 3);
    const int mblk = g / 5;
    const int ng   = g - mblk * 5;
    const int rb   = mblk * 128;

    // ---- stage-chunk setup: 26 chunks, wave w does j = w + 4i  (w<2: 7, else 6)
    const char* sp[7]; int st[7]; int dof[7];
    const int nch = (w < 2) ? 7 : 6;
#pragma unroll
    for (int i = 0; i < 7; ++i) {
        int j = w + 4 * i; if (j >= 26) j = 25;
        if (j < 10) {                      // B tile j: 1KB linear from Bpack
            sp[i]  = (const char*)Bpack + (size_t)(ng * 10 + j) * 1024 + l * 16;
            st[i]  = 50 * 1024;            // bytes per kk
            dof[i] = j * 1024;
        } else {                           // A chunk: 8 rows x 128B, source
            const int a = j - 10;          // quad-permuted so LDS is swizzled
            sp[i]  = (const char*)embed
                   + (size_t)(rb + a * 8 + (l >> 3)) * 4096
                   + (((l & 7) ^ (l >> 3)) << 4);
            st[i]  = 128;                  // bytes per kk
            dof[i] = 10240 + a * 1024;
        }
    }

    f32x4 acc[2][10];
#pragma unroll
    for (int m = 0; m < 2; ++m)
#pragma unroll
        for (int i = 0; i < 10; ++i) acc[m][i] = f32x4{0.f, 0.f, 0.f, 0.f};

    // ---- prologue: issue stage kk=0 -> buf0 (no wait here)
#pragma unroll
    for (int i = 0; i < 7; ++i) if (i < nch) {
        gload_lds16(sp[i], &bufS[0][dof[i]]);
        sp[i] += st[i];
    }

    // ---- main loop
    int cur = 0;
    for (int kk = 0; kk < 32; ++kk) {
        const int nxt = cur ^ 1;
        if (kk < 31) {
#pragma unroll
            for (int i = 0; i < 7; ++i) if (i < nch) {
                gload_lds16(sp[i], &bufS[nxt][dof[i]]);
                sp[i] += st[i];
            }
            if (w < 2) asm volatile("s_waitcnt vmcnt(7)" ::: "memory");
            else       asm volatile("s_waitcnt vmcnt(6)" ::: "memory");
        } else {
            asm volatile("s_waitcnt vmcnt(0)" ::: "memory");
        }
        __builtin_amdgcn_s_barrier();          // buf cur fully staged, all waves
        __builtin_amdgcn_sched_barrier(0);

        // A fragments: swizzled read (bank-uniform) + fp32->bf16 convert
        const float* Af = (const float*)&bufS[cur][10240];
        bf16x8 af[2];
#pragma unroll
        for (int m = 0; m < 2; ++m) {
            const int row = (w * 2 + m) * 16 + lo;
            const int sw  = (row & 7) << 2;            // float-index XOR
            const float* base = Af + row * 32;
            f32x4 v0 = *(const f32x4*)(base + ((hi * 8) ^ sw));
            f32x4 v1 = *(const f32x4*)(base + ((hi * 8 + 4) ^ sw));
            bf16x8 t;
#pragma unroll
            for (int q = 0; q < 4; ++q) { t[q] = (__bf16)v0[q]; t[4 + q] = (__bf16)v1[q]; }
            af[m] = t;
        }
#pragma unroll
        for (int i = 0; i < 10; ++i) {
            bf16x8 b = __builtin_bit_cast(bf16x8,
                *(const short8*)&bufS[cur][i * 1024 + l * 16]);
            acc[0][i] = __builtin_amdgcn_mfma_f32_16x16x32_bf16(af[0], b, acc[0][i], 0, 0, 0);
            acc[1][i] = __builtin_amdgcn_mfma_f32_16x16x32_bf16(af[1], b, acc[1][i], 0, 0, 0);
        }

        asm volatile("s_waitcnt lgkmcnt(0)" ::: "memory");   // all LDS reads done
        __builtin_amdgcn_s_barrier();          // buf cur may be overwritten next
        __builtin_amdgcn_sched_barrier(0);
        cur = nxt;
    }

    // ---- epilogue: bias + action(K=6) contribution, store bf16
#pragma unroll
    for (int m = 0; m < 2; ++m) {
        const int rbase = rb + (w * 2 + m) * 16 + hi * 4;
        float av[4][6];
#pragma unroll
        for (int r = 0; r < 4; ++r)
#pragma unroll
            for (int k = 0; k < 6; ++k) av[r][k] = action[(size_t)(rbase + r) * 6 + k];
#pragma unroll
        for (int i = 0; i < 10; ++i) {
            const int col = ng * 160 + i * 16 + lo;
            const float bias = (col < 600) ? b_ih[col] : bq1[col - 600];
            float wa[6];
            if (col < 600) {
#pragma unroll
                for (int k = 0; k < 6; ++k) wa[k] = W_ih[k * 600 + col];
            }
#pragma unroll
            for (int r = 0; r < 4; ++r) {
                float v = acc[m][i][r] + bias;
                if (col < 600) {
#pragma unroll
                    for (int k = 0; k < 6; ++k) v += av[r][k] * wa[k];
                }
                GI[(size_t)(rbase + r) * 800 + col] = f2bf(v);
            }
        }
    }
}

// ---------------- kernel 2: GRU scan, 8 waves, resident weights ----------------
#define HSTRB 232   // hS row stride in bf16 elems (K pad >=224)
#define GSTR  227   // gAll row stride in floats (odd-ish vs 32 banks)

__global__ __launch_bounds__(512, 2) void k2_scan(
    unsigned short* __restrict__ GI,           // [51200][800] bf16 (deter -> cols 0..199)
    const unsigned short* __restrict__ Whh_p,
    const float* __restrict__ b_hh,
    float* __restrict__ out)                   // [51200][350] fp32 (cols 0..199 here)
{
    __shared__ unsigned short hS[16 * HSTRB];                 // 7424 B, bf16 h
    __shared__ float gAll[3 * 16 * GSTR];                     // 43584 B
    __shared__ __align__(16) unsigned short GIbuf[2][12288];  // 49152 B

    const int tid = threadIdx.x;
    const int w = tid >> 6, l = tid & 63;
    const int lo = l & 15, hi = l >> 4;
    const int r0 = blockIdx.x * 16;

    for (int i = tid; i < 16 * HSTRB; i += 512) hS[i] = 0;

    const int t0 = w * 5;
    const int ntl = (w == 7) ? 4 : 5;
    bf16x8 wf[5][7];
#pragma unroll
    for (int i = 0; i < 5; ++i)
#pragma unroll
        for (int kk = 0; kk < 7; ++kk)
            if (i < ntl)
                wf[i][kk] = __builtin_bit_cast(bf16x8,
                    *(const short8*)&Whh_p[((kk * 39 + (t0 + i)) * 64 + l) * 8]);

    int gOff[5];
#pragma unroll
    for (int i = 0; i < 5; ++i) {
        int nt = t0 + i; if (nt > 38) nt = 38;
        const int g = nt / 13, st = nt - g * 13;
        gOff[i] = (g * 16 + hi * 4) * GSTR + st * 16 + lo;
    }

    const char* srcB[3];
#pragma unroll
    for (int i = 0; i < 3; ++i) {
        int j = (i * 8 + w) * 64 + l;
        int rj = j / 75; int cj = j - rj * 75;
        if (rj > 15) { rj = 15; cj = 74; }
        srcB[i] = (const char*)GI + (size_t)(r0 + rj) * 50 * 1600 + (size_t)cj * 16;
    }

    const int c = tid & 255;
    const int rh = tid >> 8;
    const bool act = (c < 200);
    float bh0 = 0.f, bh1 = 0.f, bh2 = 0.f;
    if (act) { bh0 = b_hh[c]; bh1 = b_hh[200 + c]; bh2 = b_hh[400 + c]; }
    float h_reg[8] = {0.f, 0.f, 0.f, 0.f, 0.f, 0.f, 0.f, 0.f};

    {
#pragma unroll
        for (int i = 0; i < 3; ++i)
            gload_lds16(srcB[i], &GIbuf[0][(i * 8 + w) * 512]);
    }
    asm volatile("s_waitcnt lgkmcnt(0)" ::: "memory");
    __builtin_amdgcn_s_barrier();
    __builtin_amdgcn_sched_barrier(0);

    for (int t = 0; t < 50; ++t) {
        const int tn = (t < 49) ? t + 1 : 49;
        const int bsel = (t + 1) & 1;
#pragma unroll
        for (int i = 0; i < 3; ++i)
            gload_lds16(srcB[i] + (size_t)tn * 1600, &GIbuf[bsel][(i * 8 + w) * 512]);

        bf16x8 hf[7];
#pragma unroll
        for (int kk = 0; kk < 7; ++kk)
            hf[kk] = __builtin_bit_cast(bf16x8,
                *(const short8*)&hS[lo * HSTRB + kk * 32 + hi * 8]);
        f32x4 acc[5];
#pragma unroll
        for (int i = 0; i < 5; ++i) acc[i] = f32x4{0.f, 0.f, 0.f, 0.f};
#pragma unroll
        for (int i = 0; i < 5; ++i) if (i < ntl)
#pragma unroll
            for (int kk = 0; kk < 7; ++kk)
                acc[i] = __builtin_amdgcn_mfma_f32_16x16x32_bf16(hf[kk], wf[i][kk], acc[i], 0, 0, 0);

#pragma unroll
        for (int i = 0; i < 5; ++i) if (i < ntl)
#pragma unroll
            for (int r = 0; r < 4; ++r)
                gAll[gOff[i] + r * GSTR] = acc[i][r];

        asm volatile("s_waitcnt lgkmcnt(0)" ::: "memory");   // B1
        __builtin_amdgcn_s_barrier();
        __builtin_amdgcn_sched_barrier(0);
        asm volatile("s_waitcnt vmcnt(3)" ::: "memory");     // GIbuf[t&1] ready
        __builtin_amdgcn_sched_barrier(0);

        if (act) {
            const unsigned short* gib = &GIbuf[t & 1][0];
#pragma unroll
            for (int rr = 0; rr < 8; ++rr) {
                const int row = rh * 8 + rr;
                const float gi_r = bf2f(gib[row * 600 + c]);
                const float gi_z = bf2f(gib[row * 600 + 200 + c]);
                const float gi_n = bf2f(gib[row * 600 + 400 + c]);
                const float gr = gi_r + gAll[(0 * 16 + row) * GSTR + c] + bh0;
                const float gz = gi_z + gAll[(1 * 16 + row) * GSTR + c] + bh1;
                const float hn = gAll[(2 * 16 + row) * GSTR + c] + bh2;
                const float rs = __builtin_amdgcn_rcpf(1.f + __expf(-gr));
                const float zz = __builtin_amdgcn_rcpf(1.f + __expf(-gz));
                const float x  = gi_n + rs * hn;
                const float e2 = __expf(-2.f * fabsf(x));
                float th = (1.f - e2) * __builtin_amdgcn_rcpf(1.f + e2);
                th = __builtin_copysignf(th, x);
                const float h = (1.f - zz) * th + zz * h_reg[rr];
                h_reg[rr] = h;
                hS[row * HSTRB + c] = f2bf(h);
                const size_t bt = (size_t)((r0 + row) * 50 + t);
                out[bt * 350 + c] = h;                 // deter fp32
                GI[bt * 800 + c]  = f2bf(h);           // deter bf16 for k3
            }
        }

        asm volatile("s_waitcnt lgkmcnt(0)" ::: "memory");   // B2
        __builtin_amdgcn_s_barrier();
        __builtin_amdgcn_sched_barrier(0);
    }
}

// ---------------- kernel 3: heads, fully parallel over 51200 rows ----------------
__global__ __launch_bounds__(256, 1) void k3_heads(
    const unsigned short* __restrict__ GI,     // deter bf16 cols 0..199, QE cols 600..799
    const unsigned short* __restrict__ Wpq1,
    const unsigned short* __restrict__ Wpq2,
    const float* __restrict__ noise,           // [51200][30]
    const float* __restrict__ bp1,
    const float* __restrict__ bp2,
    const float* __restrict__ bq2,
    float* __restrict__ out)                   // cols 200..349
{
    __shared__ unsigned short pq[2][16 * HSTRB];
    __shared__ float ost[16 * 128];

    const int tid = threadIdx.x;
    const int w = tid >> 6, l = tid & 63;
    const int lo = l & 15, hi = l >> 4;
    const int r0 = blockIdx.x * 16;

    {   unsigned short* p0 = &pq[0][0];
        for (int i = tid; i < 2 * 16 * HSTRB; i += 256) p0[i] = 0; }
    __syncthreads();

    bf16x8 af[7];
#pragma unroll
    for (int kk = 0; kk < 7; ++kk)
        af[kk] = __builtin_bit_cast(bf16x8,
            *(const short8*)&GI[(size_t)(r0 + lo) * 800 + kk * 32 + hi * 8]);

    const int h1s = (w < 2) ? 7 * w : 14 + 6 * (w - 2);
    const int h1n = (w < 2) ? 7 : 6;
    f32x4 a2[7];
#pragma unroll
    for (int i = 0; i < 7; ++i) a2[i] = f32x4{0.f, 0.f, 0.f, 0.f};
#pragma unroll
    for (int i = 0; i < 7; ++i) if (i < h1n) {
        const int nt = h1s + i;
#pragma unroll
        for (int kk = 0; kk < 7; ++kk) {
            bf16x8 b = __builtin_bit_cast(bf16x8,
                *(const short8*)&Wpq1[((kk * 26 + nt) * 64 + l) * 8]);
            a2[i] = __builtin_amdgcn_mfma_f32_16x16x32_bf16(af[kk], b, a2[i], 0, 0, 0);
        }
    }
#pragma unroll
    for (int i = 0; i < 7; ++i) if (i < h1n) {
        const int nt = h1s + i;
        const bool isq = (nt >= 13);
        const int c1 = (isq ? (nt - 13) : nt) * 16 + lo;
        if (c1 < 200) {
#pragma unroll
            for (int r = 0; r < 4; ++r) {
                const int row = hi * 4 + r;
                float v = a2[i][r];
                if (isq) v += bf2f(GI[(size_t)(r0 + row) * 800 + 600 + c1]);  // QE (incl bq1)
                else     v += bp1[c1];
                v = (v > 0.f) ? v : expm1f(v);                                 // ELU
                pq[isq ? 1 : 0][row * HSTRB + c1] = f2bf(v);
            }
        }
    }
    __syncthreads();

    const unsigned short* srcS = &pq[(w >= 2) ? 1 : 0][0];
    bf16x8 pf[7];
#pragma unroll
    for (int kk = 0; kk < 7; ++kk)
        pf[kk] = __builtin_bit_cast(bf16x8,
            *(const short8*)&srcS[lo * HSTRB + kk * 32 + hi * 8]);
    f32x4 a3[2];
    a3[0] = f32x4{0.f, 0.f, 0.f, 0.f};
    a3[1] = f32x4{0.f, 0.f, 0.f, 0.f};
#pragma unroll
    for (int i = 0; i < 2; ++i) {
        const int nt = ((w >= 2) ? 4 : 0) + (w & 1) * 2 + i;
#pragma unroll
        for (int kk = 0; kk < 7; ++kk) {
            bf16x8 b = __builtin_bit_cast(bf16x8,
                *(const short8*)&Wpq2[((kk * 8 + nt) * 64 + l) * 8]);
            a3[i] = __builtin_amdgcn_mfma_f32_16x16x32_bf16(pf[kk], b, a3[i], 0, 0, 0);
        }
    }
#pragma unroll
    for (int i = 0; i < 2; ++i) {
        const int nt = ((w >= 2) ? 4 : 0) + (w & 1) * 2 + i;
        const int cl = (nt & 3) * 16 + lo;
        if (cl < 60) {
            const float bb = (nt < 4) ? bp2[cl] : bq2[cl];
            const int obase = ((nt < 4) ? 0 : 64) + ((cl < 30) ? cl : (32 + cl - 30));
#pragma unroll
            for (int r = 0; r < 4; ++r)
                ost[(hi * 4 + r) * 128 + obase] = a3[i][r] + bb;
        }
    }
    __syncthreads();

    for (int idx = tid; idx < 16 * 150; idx += 256) {
        const int row = idx / 150;
        const int c = 200 + (idx - row * 150);
        const size_t bt = (size_t)(r0 + row);
        const float* o = &ost[row * 128];
        float v;
        if (c < 230) {
            const int j = c - 200;
            const float qs = softplusf(o[96 + j]) + 0.1f;
            v = o[64 + j] + qs * noise[bt * 30 + j];
        }
        else if (c < 260) v = o[c - 230];
        else if (c < 290) v = softplusf(o[32 + (c - 260)]) + 0.1f;
        else if (c < 320) v = o[64 + (c - 290)];
        else              v = softplusf(o[96 + (c - 320)]) + 0.1f;
        out[bt * 350 + c] = v;
    }
}

// ---------------------------------------------------------------------------
extern "C" void kernel_launch(void* const* d_in, const int* in_sizes, int n_in,
                              void* d_out, int out_size, void* d_ws, size_t ws_size,
                              hipStream_t stream)
{
    const float* action = (const float*)d_in[0];
    const float* embed  = (const float*)d_in[1];
    const float* noise  = (const float*)d_in[2];
    const float* W_ih   = (const float*)d_in[3];
    const float* W_hh   = (const float*)d_in[4];
    const float* b_ih   = (const float*)d_in[5];
    const float* b_hh   = (const float*)d_in[6];
    const float* Wp1    = (const float*)d_in[7];
    const float* bp1    = (const float*)d_in[8];
    const float* Wp2    = (const float*)d_in[9];
    const float* bp2    = (const float*)d_in[10];
    const float* Wq1    = (const float*)d_in[11];
    const float* bq1    = (const float*)d_in[12];
    const float* Wq2    = (const float*)d_in[13];
    const float* bq2    = (const float*)d_in[14];
    (void)in_sizes; (void)n_in; (void)out_size; (void)ws_size;

    char* ws = (char*)d_ws;
    unsigned short* GI    = (unsigned short*)(ws);
    unsigned short* Bpack = (unsigned short*)(ws + OFF_BPACK);
    unsigned short* Whh_p = (unsigned short*)(ws + OFF_WHH);
    unsigned short* Wpq1  = (unsigned short*)(ws + OFF_WPQ1);
    unsigned short* Wpq2  = (unsigned short*)(ws + OFF_WPQ2);
    float* outp = (float*)d_out;

    pack_kernel<<<4222, 256, 0, stream>>>(W_ih, W_hh, Wp1, Wq1, Wp2, Wq2,
                                          Bpack, Whh_p, Wpq1, Wpq2);
    k1_gi<<<2000, 256, 0, stream>>>(embed, action, W_ih, b_ih, bq1, Bpack, GI);
    k2_scan<<<64, 512, 0, stream>>>(GI, Whh_p, b_hh, outp);
    k3_heads<<<3200, 256, 0, stream>>>(GI, Wpq1, Wpq2, noise, bp1, bp2, bq2, outp);
}